// Round 7
// baseline (82560.107 us; speedup 1.0000x reference)
//
#include <hip/hip_runtime.h>
#include <math.h>

typedef __attribute__((ext_vector_type(8))) short s16x8;
typedef __attribute__((ext_vector_type(8))) _Float16 f16x8;
typedef __attribute__((ext_vector_type(16))) float f32x16;
typedef unsigned long long u64;
typedef unsigned short u16;

#define NBLK 256          // worker blocks
#define NGRID 257         // workers + 1 aggregator
#define NTHR 512
#define EPOCHS 516        // 2 layers * (1 entry + 256 steps + 1 end)

constexpr int HSZ = 32 * 2048;  // one h buffer, f16 elems

__device__ __forceinline__ float sigm(float v) { return 1.0f / (1.0f + expf(-v)); }

__device__ __forceinline__ unsigned short bf16_rne(float x) {
    unsigned u = __float_as_uint(x);
    return (unsigned short)((u + 0x7FFFu + ((u >> 16) & 1u)) >> 16);
}
__device__ __forceinline__ void split2(float x, unsigned short& hi, unsigned short& lo) {
    unsigned u = __float_as_uint(x);
    hi = (unsigned short)(u >> 16);
    float hf = __uint_as_float(u & 0xFFFF0000u);
    lo = bf16_rne(x - hf);
}
__device__ __forceinline__ void split8(const float* f, s16x8& h, s16x8& l) {
    #pragma unroll
    for (int i = 0; i < 8; ++i) {
        unsigned short hh, ll;
        split2(f[i], hh, ll);
        h[i] = (short)hh; l[i] = (short)ll;
    }
}

// ---- agent-scope (L3 coherence point) accessors for cross-block data ----
__device__ __forceinline__ u64 ald64(const void* p) {
    return __hip_atomic_load((const u64*)p, __ATOMIC_RELAXED, __HIP_MEMORY_SCOPE_AGENT);
}
__device__ __forceinline__ void ast64(u16* p, u64 v) {
    __hip_atomic_store((u64*)p, v, __ATOMIC_RELAXED, __HIP_MEMORY_SCOPE_AGENT);
}
__device__ __forceinline__ void ast32(float* p, float v) {
    __hip_atomic_store((unsigned*)p, __float_as_uint(v), __ATOMIC_RELAXED, __HIP_MEMORY_SCOPE_AGENT);
}
__device__ __forceinline__ f16x8 ald_f16x8(const u16* p) {
    union { u64 q[2]; f16x8 v; } u;
    u.q[0] = ald64(p);
    u.q[1] = ald64(p + 4);
    return u.v;
}

__device__ __forceinline__ void wait_rel(const unsigned* rel, unsigned e) {
    if (threadIdx.x == 0) {
        while (__hip_atomic_load(rel, __ATOMIC_RELAXED, __HIP_MEMORY_SCOPE_AGENT) < e)
            __builtin_amdgcn_s_sleep(1);
    }
    __syncthreads();
}

// ---------- precompute: transpose [R][C] fp32 -> [C][R] bf16 hi/lo ----------
__global__ void transpose_split(const float* __restrict__ in,
                                u16* __restrict__ outHi, u16* __restrict__ outLo,
                                int R, int C) {
    __shared__ float tile[32][33];
    const int c0 = blockIdx.x * 32, r0 = blockIdx.y * 32;
    const int tid = threadIdx.x;  // 256
    {
        int r = tid >> 3, q = (tid & 7) * 4;
        float4 v = *(const float4*)(in + (size_t)(r0 + r) * C + c0 + q);
        tile[q + 0][r] = v.x; tile[q + 1][r] = v.y;
        tile[q + 2][r] = v.z; tile[q + 3][r] = v.w;
    }
    __syncthreads();
    {
        int c = tid >> 3, q = (tid & 7) * 4;
        ushort4 h, l;
        unsigned short hh, ll;
        split2(tile[c][q + 0], hh, ll); h.x = hh; l.x = ll;
        split2(tile[c][q + 1], hh, ll); h.y = hh; l.y = ll;
        split2(tile[c][q + 2], hh, ll); h.z = hh; l.z = ll;
        split2(tile[c][q + 3], hh, ll); h.w = hh; l.w = ll;
        size_t o = (size_t)(c0 + c) * R + r0 + q;
        *(ushort4*)(outHi + o) = h;
        *(ushort4*)(outLo + o) = l;
    }
}

// ---------- precompute: transpose [R][C] fp32 -> [C][R] f16 ----------
__global__ void transpose_f16(const float* __restrict__ in, u16* __restrict__ outp,
                              int R, int C) {
    __shared__ float tile[32][33];
    const int c0 = blockIdx.x * 32, r0 = blockIdx.y * 32;
    const int tid = threadIdx.x;  // 256
    {
        int r = tid >> 3, q = (tid & 7) * 4;
        float4 v = *(const float4*)(in + (size_t)(r0 + r) * C + c0 + q);
        tile[q + 0][r] = v.x; tile[q + 1][r] = v.y;
        tile[q + 2][r] = v.z; tile[q + 3][r] = v.w;
    }
    __syncthreads();
    {
        int c = tid >> 3, q = (tid & 7) * 4;
        ushort4 o;
        o.x = __builtin_bit_cast(u16, (_Float16)tile[c][q + 0]);
        o.y = __builtin_bit_cast(u16, (_Float16)tile[c][q + 1]);
        o.z = __builtin_bit_cast(u16, (_Float16)tile[c][q + 2]);
        o.w = __builtin_bit_cast(u16, (_Float16)tile[c][q + 3]);
        *(ushort4*)(outp + (size_t)(c0 + c) * R + r0 + q) = o;
    }
}

// ---------- precompute: Qt[8192][2048] f16 = (P[2048][640] @ Wm[640][8192])^T ----------
__global__ void __launch_bounds__(256) qgemm(const float* __restrict__ P,
    const u16* __restrict__ WH, const u16* __restrict__ WL,
    u16* __restrict__ Qt) {
    const int tid = threadIdx.x;
    const int wid = tid >> 6, lane = tid & 63;
    const int n = lane & 31, kg = lane >> 5;
    const int tile = blockIdx.x * 4 + wid;
    const int ct = tile & 255, kt = tile >> 8;
    const int col = ct * 32 + n;
    const int krow = kt * 32 + n;

    f32x16 acc;
    #pragma unroll
    for (int r = 0; r < 16; ++r) acc[r] = 0.f;

    const float* ap = P + (size_t)krow * 640 + kg * 8;
    const u16* bhp = WH + (size_t)col * 1280 + 640 + kg * 8;
    const u16* blp = WL + (size_t)col * 1280 + 640 + kg * 8;
    #pragma unroll 4
    for (int ks = 0; ks < 40; ++ks) {
        float4 v0 = *(const float4*)(ap + ks * 16);
        float4 v1 = *(const float4*)(ap + ks * 16 + 4);
        float f[8] = {v0.x, v0.y, v0.z, v0.w, v1.x, v1.y, v1.z, v1.w};
        s16x8 ah, al;
        split8(f, ah, al);
        s16x8 bh = *(const s16x8*)(bhp + ks * 16);
        s16x8 bl = *(const s16x8*)(blp + ks * 16);
        acc = __builtin_amdgcn_mfma_f32_32x32x16_bf16(ah, bh, acc, 0, 0, 0);
        acc = __builtin_amdgcn_mfma_f32_32x32x16_bf16(ah, bl, acc, 0, 0, 0);
        acc = __builtin_amdgcn_mfma_f32_32x32x16_bf16(al, bh, acc, 0, 0, 0);
    }
    u16* qrow = Qt + (size_t)col * 2048 + kt * 32 + 4 * kg;
    #pragma unroll
    for (int q = 0; q < 4; ++q) {
        ushort4 o;
        o.x = __builtin_bit_cast(u16, (_Float16)acc[4 * q + 0]);
        o.y = __builtin_bit_cast(u16, (_Float16)acc[4 * q + 1]);
        o.z = __builtin_bit_cast(u16, (_Float16)acc[4 * q + 2]);
        o.w = __builtin_bit_cast(u16, (_Float16)acc[4 * q + 3]);
        *(ushort4*)(qrow + 8 * q) = o;
    }
}

// ---------- main persistent kernel: one handoff per step, aggregator barrier ----------
// __launch_bounds__(512, 4): forces VGPR<=128 -> 2 blocks/CU -> 512 slots >= 257.
// (R6 deadlocked: VGPR crept past 128 -> 1 block/CU -> aggregator block never scheduled.)
__global__ void __launch_bounds__(NTHR, 4) lstm_q(
    const float* __restrict__ x,
    const float* __restrict__ bias0, const float* __restrict__ bias1,
    const u16* __restrict__ WH0, const u16* __restrict__ WL0,
    const u16* __restrict__ WH1, const u16* __restrict__ WL1,
    const u16* __restrict__ Qt0, const u16* __restrict__ Qt1,
    const u16* __restrict__ Pt0, const u16* __restrict__ Pt1,
    u16* __restrict__ hb,      // [3][32][2048] f16
    float* out, unsigned* arr, unsigned* rel) {
    const int tid = threadIdx.x, bid = blockIdx.x;

    // ======== aggregator block: poll arrives, publish release, exit ========
    if (bid == NBLK) {
        if (tid < 64) {
            const unsigned* base = arr + (size_t)tid * 64;  // flags 4*tid .. 4*tid+3 (1/64B line)
            for (unsigned e = 1; e <= EPOCHS; ++e) {
                for (;;) {
                    bool ok = (__hip_atomic_load(base + 0,  __ATOMIC_RELAXED, __HIP_MEMORY_SCOPE_AGENT) >= e) &&
                              (__hip_atomic_load(base + 16, __ATOMIC_RELAXED, __HIP_MEMORY_SCOPE_AGENT) >= e) &&
                              (__hip_atomic_load(base + 32, __ATOMIC_RELAXED, __HIP_MEMORY_SCOPE_AGENT) >= e) &&
                              (__hip_atomic_load(base + 48, __ATOMIC_RELAXED, __HIP_MEMORY_SCOPE_AGENT) >= e);
                    if (__all(ok)) break;
                    __builtin_amdgcn_s_sleep(1);
                }
                if (tid == 0)
                    __hip_atomic_store(rel, e, __ATOMIC_RELAXED, __HIP_MEMORY_SCOPE_AGENT);
            }
        }
        return;
    }

    __shared__ float part[8][64][20];
    __shared__ float zb[32][33];
    __shared__ u16 hst[32][8];

    const int wid = tid >> 6, lane = tid & 63;
    const int n = lane & 31, kg = lane >> 5;
    unsigned e = 0;

    const int colmap = (n >> 3) * 2048 + bid * 8 + (n & 7);
    const size_t wOffX = (size_t)colmap * 1280 + wid * 80 + kg * 8;   // Wx k-slice
    const size_t qOff  = (size_t)colmap * 2048 + wid * 256 + kg * 8;  // Qt slice
    const size_t aXOff = (size_t)n * (256 * 640) + wid * 80 + kg * 8; // + t*640
    const size_t hROff = (size_t)n * 2048 + wid * 256 + kg * 8;       // h frag base

    // reduce mapping: D col=lane&31, row=(reg&3)+8*(reg>>2)+4*(lane>>5)
    const int rn = tid >> 4, rm0 = (tid & 15) * 2;
    const int ch = tid >> 5, cb = tid & 31;   // cell mapping (tid<256)

    const bool isTeam = bid < 40;
    const int tb = (bid < 20) ? bid : bid - 20;
    const int myPar = (bid < 20) ? 0 : 1;
    const size_t pOff = (size_t)(tb * 32 + n) * 2048 + wid * 256 + kg * 8;

    for (int layer = 0; layer < 2; ++layer) {
        const bool l0 = (layer == 0);
        const u16* WH = l0 ? WH0 : WH1;
        const u16* WL = l0 ? WL0 : WL1;
        const u16* Qt = l0 ? Qt0 : Qt1;
        const u16* Pt = l0 ? Pt0 : Pt1;
        const float bv = (l0 ? bias0 : bias1)[(rn >> 3) * 2048 + bid * 8 + (rn & 7)];
        const float* inp = l0 ? x : (const float*)out;  // plain loads; safe: each line read once, written only via sc1

        // Q fragments register-resident for the whole layer (64 VGPRs)
        f16x8 qf[16];
        #pragma unroll
        for (int ks = 0; ks < 16; ++ks) qf[ks] = *(const f16x8*)(Qt + qOff + ks * 16);

        float creg = 0.f;

        // layer-entry barrier (layer 1: gates on all of layer 0's out)
        ++e;
        __syncthreads();
        if (tid == 0)
            __hip_atomic_store(arr + (size_t)bid * 16, e, __ATOMIC_RELEASE, __HIP_MEMORY_SCOPE_AGENT);
        wait_rel(rel, e);

        auto xpart = [&](int t) -> f32x16 {
            f32x16 a;
            #pragma unroll
            for (int r = 0; r < 16; ++r) a[r] = 0.f;
            const float* xb = inp + aXOff + (size_t)t * 640;
            const u16* whx = WH + wOffX;
            const u16* wlx = WL + wOffX;
            #pragma unroll
            for (int ks = 0; ks < 5; ++ks) {
                float4 v0 = *(const float4*)(xb + ks * 16);
                float4 v1 = *(const float4*)(xb + ks * 16 + 4);
                float f[8] = {v0.x, v0.y, v0.z, v0.w, v1.x, v1.y, v1.z, v1.w};
                s16x8 ah, al;
                split8(f, ah, al);
                s16x8 bh = *(const s16x8*)(whx + ks * 16);
                s16x8 bl = *(const s16x8*)(wlx + ks * 16);
                a = __builtin_amdgcn_mfma_f32_32x32x16_bf16(ah, bh, a, 0, 0, 0);
                a = __builtin_amdgcn_mfma_f32_32x32x16_bf16(ah, bl, a, 0, 0, 0);
                a = __builtin_amdgcn_mfma_f32_32x32x16_bf16(al, bh, a, 0, 0, 0);
            }
            return a;
        };

        f32x16 zacc = xpart(0);

        for (int t = 0; t < 256; ++t) {
            if (t > 0) wait_rel(rel, e);   // h(t-1) slices all published

            const bool doProj = isTeam && (t > 0) && (((t - 1) & 1) == myPar);
            f32x16 acc = zacc;
            f32x16 pacc;
            if (t > 0) {
                const u16* hc = hb + (size_t)((t + 2) % 3) * HSZ + hROff;  // buf (t-1)%3
                if (doProj) {
                    #pragma unroll
                    for (int r = 0; r < 16; ++r) pacc[r] = 0.f;
                    #pragma unroll
                    for (int ks = 0; ks < 16; ++ks) {
                        f16x8 a = ald_f16x8(hc + ks * 16);  // shared by Q-GEMM and proj
                        acc  = __builtin_amdgcn_mfma_f32_32x32x16_f16(a, qf[ks], acc, 0, 0, 0);
                        f16x8 pb = *(const f16x8*)(Pt + pOff + ks * 16);
                        pacc = __builtin_amdgcn_mfma_f32_32x32x16_f16(a, pb, pacc, 0, 0, 0);
                    }
                } else {
                    #pragma unroll
                    for (int ks = 0; ks < 16; ++ks)
                        acc = __builtin_amdgcn_mfma_f32_32x32x16_f16(ald_f16x8(hc + ks * 16), qf[ks], acc, 0, 0, 0);
                }
            }

            // cross-wave K reduce -> z
            #pragma unroll
            for (int r = 0; r < 4; r++) {
                float4 v;
                v.x = acc[4 * r + 0]; v.y = acc[4 * r + 1];
                v.z = acc[4 * r + 2]; v.w = acc[4 * r + 3];
                *(float4*)&part[wid][lane][4 * r] = v;
            }
            __syncthreads();
            #pragma unroll
            for (int j = 0; j < 2; j++) {
                int m = rm0 + j;
                int lp = rn + 32 * ((m >> 2) & 1);
                int rg = (m & 3) + 4 * (m >> 3);
                float s = 0.f;
                #pragma unroll
                for (int w = 0; w < 8; w++) s += part[w][lp][rg];
                zb[rn][m] = s + bv;
            }
            __syncthreads();

            // stash proj accumulator into part (dead here) BEFORE the publish barrier:
            // ends pacc's live range pre-publish (register-peak reduction).
            if (doProj) {
                #pragma unroll
                for (int r = 0; r < 4; r++) {
                    float4 v;
                    v.x = pacc[4 * r + 0]; v.y = pacc[4 * r + 1];
                    v.z = pacc[4 * r + 2]; v.w = pacc[4 * r + 3];
                    *(float4*)&part[wid][lane][4 * r] = v;
                }
            }

            // cell update (gate order i, j, f, o); h -> LDS stage as f16
            if (tid < 256) {
                float zi = zb[0 * 8 + ch][cb];
                float zj = zb[1 * 8 + ch][cb];
                float zf = zb[2 * 8 + ch][cb];
                float zo = zb[3 * 8 + ch][cb];
                float cn = sigm(zf + 1.0f) * creg + sigm(zi) * tanhf(zj);
                creg = cn;
                float hv = sigm(zo) * tanhf(cn);
                hst[cb][ch] = __builtin_bit_cast(u16, (_Float16)hv);
            }
            __syncthreads();   // hst + part(pacc) visible
            ++e;
            if (tid < 64) {  // wave 0: publish h slice + fast arrive
                int b = tid >> 1, hf = tid & 1;
                u64 v = *(const u64*)&hst[b][hf * 4];
                ast64(hb + (size_t)(t % 3) * HSZ + (size_t)b * 2048 + bid * 8 + hf * 4, v);
                asm volatile("s_waitcnt vmcnt(0)" ::: "memory");
                if (tid == 0)
                    __hip_atomic_store(arr + (size_t)bid * 16, e,
                                       __ATOMIC_RELAXED, __HIP_MEMORY_SCOPE_AGENT);
            }

            // proj flush: reduce stashed pacc from part, write out (off critical path)
            if (doProj) {
                #pragma unroll
                for (int j = 0; j < 2; j++) {
                    int m = rm0 + j;
                    int lp = rn + 32 * ((m >> 2) & 1);
                    int rg = (m & 3) + 4 * (m >> 3);
                    float s = 0.f;
                    #pragma unroll
                    for (int w = 0; w < 8; w++) s += part[w][lp][rg];
                    ast32(out + ((size_t)m * 256 + (t - 1)) * 640 + tb * 32 + rn, s);
                }
            }
            if (t < 255) zacc = xpart(t + 1);   // overlapped with others' arrival
        }

        // finish proj(255) (odd -> team B), then layer boundary
        wait_rel(rel, e);
        if (isTeam && myPar == 1) {
            const u16* hc = hb + (size_t)(255 % 3) * HSZ + hROff;
            f32x16 pacc;
            #pragma unroll
            for (int r = 0; r < 16; ++r) pacc[r] = 0.f;
            #pragma unroll
            for (int ks = 0; ks < 16; ++ks) {
                f16x8 a = ald_f16x8(hc + ks * 16);
                f16x8 pb = *(const f16x8*)(Pt + pOff + ks * 16);
                pacc = __builtin_amdgcn_mfma_f32_32x32x16_f16(a, pb, pacc, 0, 0, 0);
            }
            __syncthreads();
            #pragma unroll
            for (int r = 0; r < 4; r++) {
                float4 v;
                v.x = pacc[4 * r + 0]; v.y = pacc[4 * r + 1];
                v.z = pacc[4 * r + 2]; v.w = pacc[4 * r + 3];
                *(float4*)&part[wid][lane][4 * r] = v;
            }
            __syncthreads();
            #pragma unroll
            for (int j = 0; j < 2; j++) {
                int m = rm0 + j;
                int lp = rn + 32 * ((m >> 2) & 1);
                int rg = (m & 3) + 4 * (m >> 3);
                float s = 0.f;
                #pragma unroll
                for (int w = 0; w < 8; w++) s += part[w][lp][rg];
                ast32(out + ((size_t)m * 256 + 255) * 640 + tb * 32 + rn, s);
            }
        }
        ++e;
        __syncthreads();   // drains all proj stores (vmcnt before s_barrier)
        if (tid == 0)
            __hip_atomic_store(arr + (size_t)bid * 16, e, __ATOMIC_RELEASE, __HIP_MEMORY_SCOPE_AGENT);
        wait_rel(rel, e);  // all `out` writes for this layer visible
    }
}

// ---------- fallback (R1-style) if ws too small or capacity insufficient ----------
__device__ __forceinline__ void grid_bar_slow(unsigned int* bar, unsigned int& epoch) {
    __syncthreads();
    epoch++;
    if (threadIdx.x == 0) {
        __threadfence();
        atomicAdd(bar, 1u);
        const unsigned int target = epoch * NBLK;
        while (__hip_atomic_load(bar, __ATOMIC_RELAXED, __HIP_MEMORY_SCOPE_AGENT) < target)
            __builtin_amdgcn_s_sleep(1);
        __threadfence();
    }
    __syncthreads();
}

__global__ void __launch_bounds__(NTHR, 1) lstm_fb(
    const float* __restrict__ x,
    const float* __restrict__ W0, const float* __restrict__ b0, const float* __restrict__ Pr0,
    const float* __restrict__ W1, const float* __restrict__ b1, const float* __restrict__ Pr1,
    float* out, float* ws) {
    const int tid = threadIdx.x;
    const int bid = blockIdx.x;
    unsigned int* bar = (unsigned int*)ws;
    float* mbuf0 = ws + 1024;
    float* mbuf1 = mbuf0 + 32 * 640;
    float* hws = mbuf1 + 32 * 640;
    __shared__ float zbuf[32 * 33];
    __shared__ float pred[512];
    unsigned int epoch = 0;
    const int c_idx = tid & 31;
    const int bg = tid >> 5;
    const int b0r = bg * 2;
    const int col = (c_idx >> 3) * 2048 + bid * 8 + (c_idx & 7);
    const int ch = tid >> 5;
    const int cb = tid & 31;
    const int p_s = (bid * 640) / NBLK;
    const int p_e = ((bid + 1) * 640) / NBLK;
    const int np = p_e - p_s;
    const int kq_n = (np == 2) ? 8 : 4;
    const int klen = 2048 / kq_n;
    const int pg = tid >> 5;
    const bool pact = pg < np * kq_n;
    const int pj = pact ? (pg % np) : 0;
    const int kq = pact ? (pg / np) : 0;
    for (int layer = 0; layer < 2; ++layer) {
        const float* W = layer ? W1 : W0;
        const float* bbv = layer ? b1 : b0;
        const float* Pr = layer ? Pr1 : Pr0;
        const float* inb = layer ? (const float*)out : x;
        for (int i = bid * NTHR + tid; i < 32 * 640; i += NBLK * NTHR) mbuf0[i] = 0.0f;
        float creg = 0.0f;
        grid_bar_slow(bar, epoch);
        const float bias = bbv[col];
        for (int t = 0; t < 256; ++t) {
            float* mcur = (t & 1) ? mbuf1 : mbuf0;
            float* mnxt = (t & 1) ? mbuf0 : mbuf1;
            const float* in0 = inb + (size_t)(b0r * 256 + t) * 640;
            const float* in1 = in0 + (size_t)256 * 640;
            const float* wp = W + col;
            float a0 = 0.f, a1 = 0.f;
            #pragma unroll 4
            for (int k = 0; k < 640; k += 4) {
                float4 u0 = *(const float4*)(in0 + k);
                float4 u1 = *(const float4*)(in1 + k);
                float w0 = wp[(size_t)(k + 0) * 8192], w1 = wp[(size_t)(k + 1) * 8192];
                float w2 = wp[(size_t)(k + 2) * 8192], w3 = wp[(size_t)(k + 3) * 8192];
                a0 += w0 * u0.x + w1 * u0.y + w2 * u0.z + w3 * u0.w;
                a1 += w0 * u1.x + w1 * u1.y + w2 * u1.z + w3 * u1.w;
            }
            const float* q0 = mcur + (size_t)b0r * 640;
            const float* q1 = q0 + 640;
            #pragma unroll 4
            for (int k = 0; k < 640; k += 4) {
                float4 u0 = *(const float4*)(q0 + k);
                float4 u1 = *(const float4*)(q1 + k);
                float w0 = wp[(size_t)(640 + k + 0) * 8192], w1 = wp[(size_t)(640 + k + 1) * 8192];
                float w2 = wp[(size_t)(640 + k + 2) * 8192], w3 = wp[(size_t)(640 + k + 3) * 8192];
                a0 += w0 * u0.x + w1 * u0.y + w2 * u0.z + w3 * u0.w;
                a1 += w0 * u1.x + w1 * u1.y + w2 * u1.z + w3 * u1.w;
            }
            zbuf[c_idx * 33 + b0r + 0] = a0 + bias;
            zbuf[c_idx * 33 + b0r + 1] = a1 + bias;
            __syncthreads();
            if (tid < 256) {
                float zi = zbuf[(0 * 8 + ch) * 33 + cb];
                float zj = zbuf[(1 * 8 + ch) * 33 + cb];
                float zf = zbuf[(2 * 8 + ch) * 33 + cb];
                float zo = zbuf[(3 * 8 + ch) * 33 + cb];
                float cn = sigm(zf + 1.0f) * creg + sigm(zi) * tanhf(zj);
                creg = cn;
                hws[(size_t)(bid * 8 + ch) * 32 + cb] = sigm(zo) * tanhf(cn);
            }
            grid_bar_slow(bar, epoch);
            if (pact) {
                const int p = p_s + pj;
                const float* pp = Pr + p;
                const int k0 = kq * klen;
                float s = 0.f;
                #pragma unroll 4
                for (int k = k0; k < k0 + klen; ++k) s += hws[(size_t)k * 32 + cb] * pp[(size_t)k * 640];
                pred[(pj * 32 + cb) * kq_n + kq] = s;
            }
            __syncthreads();
            if (tid < np * 32) {
                float s = 0.f;
                for (int q2 = 0; q2 < kq_n; ++q2) s += pred[tid * kq_n + q2];
                const int p = p_s + (tid >> 5);
                const int b = tid & 31;
                mnxt[(size_t)b * 640 + p] = s;
                out[((size_t)b * 256 + t) * 640 + p] = s;
            }
            grid_bar_slow(bar, epoch);
        }
    }
}

extern "C" void kernel_launch(void* const* d_in, const int* in_sizes, int n_in,
                              void* d_out, int out_size, void* d_ws, size_t ws_size,
                              hipStream_t stream) {
    const float* x   = (const float*)d_in[0];
    const float* W0  = (const float*)d_in[1];
    const float* b0  = (const float*)d_in[2];
    const float* P0  = (const float*)d_in[3];
    const float* W1  = (const float*)d_in[4];
    const float* b1  = (const float*)d_in[5];
    const float* P1  = (const float*)d_in[6];
    float* out = (float*)d_out;

    // ws layout (bytes, 256-aligned chunks)
    size_t off = 0;
    auto alloc = [&](size_t bytes) { size_t o = off; off += (bytes + 255) & ~(size_t)255; return o; };
    const size_t oBar = alloc(32768);             // arr: 256 flags x 64B; rel @ +16384
    const size_t szW  = (size_t)8192 * 1280 * 2;  // Wt bf16 plane
    const size_t szQ  = (size_t)8192 * 2048 * 2;  // Qt f16
    const size_t szPt = (size_t)640 * 2048 * 2;   // Pt f16
    const size_t oWH0 = alloc(szW), oWL0 = alloc(szW), oWH1 = alloc(szW), oWL1 = alloc(szW);
    const size_t oQt0 = alloc(szQ), oQt1 = alloc(szQ);
    const size_t oPt0 = alloc(szPt), oPt1 = alloc(szPt);
    const size_t oH   = alloc((size_t)3 * HSZ * 2);
    const size_t need = off;

    hipMemsetAsync(d_ws, 0, 32768, stream);  // barrier flags start at 0 every call

    // capacity guard: persistent kernel needs all 257 blocks co-resident
    int blocksPerCU = 0;
    hipError_t occErr = hipOccupancyMaxActiveBlocksPerMultiprocessor(
        &blocksPerCU, (const void*)lstm_q, NTHR, 0);
    const bool capOK = (occErr == hipSuccess) && (blocksPerCU * 256 >= NGRID);

    if (ws_size < need || !capOK) {  // fallback path (~0.5 MB ws)
        float* ws = (float*)d_ws;
        void* args[] = {(void*)&x, (void*)&W0, (void*)&b0, (void*)&P0,
                        (void*)&W1, (void*)&b1, (void*)&P1, (void*)&out, (void*)&ws};
        hipError_t err = hipLaunchCooperativeKernel((const void*)lstm_fb,
                                                    dim3(NBLK), dim3(NTHR), args, 0, stream);
        if (err != hipSuccess)
            lstm_fb<<<dim3(NBLK), dim3(NTHR), 0, stream>>>(x, W0, b0, P0, W1, b1, P1, out, ws);
        return;
    }

    char* w = (char*)d_ws;
    u16 *WH0p = (u16*)(w + oWH0), *WL0p = (u16*)(w + oWL0);
    u16 *WH1p = (u16*)(w + oWH1), *WL1p = (u16*)(w + oWL1);
    u16 *Qt0p = (u16*)(w + oQt0), *Qt1p = (u16*)(w + oQt1);
    u16 *Pt0p = (u16*)(w + oPt0), *Pt1p = (u16*)(w + oPt1);
    u16 *hbp  = (u16*)(w + oH);
    unsigned* arrp = (unsigned*)(w + oBar);
    unsigned* relp = (unsigned*)(w + oBar + 16384);

    // precompute: weight transposes + Q = P @ Wm (inside the graph, every call)
    transpose_split<<<dim3(256, 40), 256, 0, stream>>>(W0, WH0p, WL0p, 1280, 8192);
    transpose_split<<<dim3(256, 40), 256, 0, stream>>>(W1, WH1p, WL1p, 1280, 8192);
    transpose_f16<<<dim3(20, 64), 256, 0, stream>>>(P0, Pt0p, 2048, 640);
    transpose_f16<<<dim3(20, 64), 256, 0, stream>>>(P1, Pt1p, 2048, 640);
    qgemm<<<dim3(4096), 256, 0, stream>>>(P0, WH0p, WL0p, Qt0p);
    qgemm<<<dim3(4096), 256, 0, stream>>>(P1, WH1p, WL1p, Qt1p);

    const float *b0c = b0, *b1c = b1;
    void* args[] = {(void*)&x, (void*)&b0c, (void*)&b1c,
                    (void*)&WH0p, (void*)&WL0p, (void*)&WH1p, (void*)&WL1p,
                    (void*)&Qt0p, (void*)&Qt1p, (void*)&Pt0p, (void*)&Pt1p,
                    (void*)&hbp, (void*)&out, (void*)&arrp, (void*)&relp};
    hipError_t err = hipLaunchCooperativeKernel((const void*)lstm_q,
                                                dim3(NGRID), dim3(NTHR), args, 0, stream);
    if (err != hipSuccess)
        lstm_q<<<dim3(NGRID), dim3(NTHR), 0, stream>>>(
            x, b0c, b1c, WH0p, WL0p, WH1p, WL1p, Qt0p, Qt1p, Pt0p, Pt1p,
            hbp, out, arrp, relp);
}

// Round 8
// 10442.889 us; speedup vs baseline: 7.9059x; 7.9059x over previous
//
#include <hip/hip_runtime.h>
#include <math.h>

typedef __attribute__((ext_vector_type(8))) short s16x8;
typedef __attribute__((ext_vector_type(8))) _Float16 f16x8;
typedef __attribute__((ext_vector_type(16))) float f32x16;
typedef unsigned long long u64;
typedef unsigned short u16;

#define NBLK 256
#define NTHR 512

constexpr int HSZ2 = 32 * 2048;  // one h buffer, f16 elems
constexpr int MSZ  = 32 * 640;   // one m0 buffer, f32 elems

__device__ __forceinline__ float sigm(float v) { return 1.0f / (1.0f + expf(-v)); }

__device__ __forceinline__ unsigned short bf16_rne(float x) {
    unsigned u = __float_as_uint(x);
    return (unsigned short)((u + 0x7FFFu + ((u >> 16) & 1u)) >> 16);
}
__device__ __forceinline__ void split2(float x, unsigned short& hi, unsigned short& lo) {
    unsigned u = __float_as_uint(x);
    hi = (unsigned short)(u >> 16);
    float hf = __uint_as_float(u & 0xFFFF0000u);
    lo = bf16_rne(x - hf);
}
__device__ __forceinline__ void split8(const float* f, s16x8& h, s16x8& l) {
    #pragma unroll
    for (int i = 0; i < 8; ++i) {
        unsigned short hh, ll;
        split2(f[i], hh, ll);
        h[i] = (short)hh; l[i] = (short)ll;
    }
}

// ---- agent-scope (L3 coherence point) accessors for cross-block data ----
__device__ __forceinline__ u64 ald64(const void* p) {
    return __hip_atomic_load((const u64*)p, __ATOMIC_RELAXED, __HIP_MEMORY_SCOPE_AGENT);
}
__device__ __forceinline__ void ast64(u16* p, u64 v) {
    __hip_atomic_store((u64*)p, v, __ATOMIC_RELAXED, __HIP_MEMORY_SCOPE_AGENT);
}
__device__ __forceinline__ void ast32(float* p, float v) {
    __hip_atomic_store((unsigned*)p, __float_as_uint(v), __ATOMIC_RELAXED, __HIP_MEMORY_SCOPE_AGENT);
}
__device__ __forceinline__ f16x8 ald_f16x8(const u16* p) {
    union { u64 q[2]; f16x8 v; } u;
    u.q[0] = ald64(p);
    u.q[1] = ald64(p + 4);
    return u.v;
}
__device__ __forceinline__ void ld8f(const float* p, float* f) {
    #pragma unroll
    for (int i = 0; i < 4; ++i) {
        union { u64 q; float g[2]; } u;
        u.q = ald64(p + 2 * i);
        f[2 * i] = u.g[0]; f[2 * i + 1] = u.g[1];
    }
}

// ---- R5-proven all-poll barrier pieces ----
__device__ __forceinline__ void pollall(const unsigned* arr, unsigned e) {
    if (threadIdx.x < 64) {
        const int i0 = (int)threadIdx.x * 4;
        for (;;) {
            bool ok = (__hip_atomic_load(arr + i0 + 0, __ATOMIC_RELAXED, __HIP_MEMORY_SCOPE_AGENT) >= e) &&
                      (__hip_atomic_load(arr + i0 + 1, __ATOMIC_RELAXED, __HIP_MEMORY_SCOPE_AGENT) >= e) &&
                      (__hip_atomic_load(arr + i0 + 2, __ATOMIC_RELAXED, __HIP_MEMORY_SCOPE_AGENT) >= e) &&
                      (__hip_atomic_load(arr + i0 + 3, __ATOMIC_RELAXED, __HIP_MEMORY_SCOPE_AGENT) >= e);
            if (__all(ok)) break;
            __builtin_amdgcn_s_sleep(1);
        }
    }
    __syncthreads();
}

// ---------- precompute: transpose [R][C] fp32 -> [C][R] bf16 hi/lo ----------
__global__ void transpose_split(const float* __restrict__ in,
                                u16* __restrict__ outHi, u16* __restrict__ outLo,
                                int R, int C) {
    __shared__ float tile[32][33];
    const int c0 = blockIdx.x * 32, r0 = blockIdx.y * 32;
    const int tid = threadIdx.x;  // 256
    {
        int r = tid >> 3, q = (tid & 7) * 4;
        float4 v = *(const float4*)(in + (size_t)(r0 + r) * C + c0 + q);
        tile[q + 0][r] = v.x; tile[q + 1][r] = v.y;
        tile[q + 2][r] = v.z; tile[q + 3][r] = v.w;
    }
    __syncthreads();
    {
        int c = tid >> 3, q = (tid & 7) * 4;
        ushort4 h, l;
        unsigned short hh, ll;
        split2(tile[c][q + 0], hh, ll); h.x = hh; l.x = ll;
        split2(tile[c][q + 1], hh, ll); h.y = hh; l.y = ll;
        split2(tile[c][q + 2], hh, ll); h.z = hh; l.z = ll;
        split2(tile[c][q + 3], hh, ll); h.w = hh; l.w = ll;
        size_t o = (size_t)(c0 + c) * R + r0 + q;
        *(ushort4*)(outHi + o) = h;
        *(ushort4*)(outLo + o) = l;
    }
}

// ---------- precompute: transpose [R][C] fp32 -> [C][R] f16 ----------
__global__ void transpose_f16(const float* __restrict__ in, u16* __restrict__ outp,
                              int R, int C) {
    __shared__ float tile[32][33];
    const int c0 = blockIdx.x * 32, r0 = blockIdx.y * 32;
    const int tid = threadIdx.x;  // 256
    {
        int r = tid >> 3, q = (tid & 7) * 4;
        float4 v = *(const float4*)(in + (size_t)(r0 + r) * C + c0 + q);
        tile[q + 0][r] = v.x; tile[q + 1][r] = v.y;
        tile[q + 2][r] = v.z; tile[q + 3][r] = v.w;
    }
    __syncthreads();
    {
        int c = tid >> 3, q = (tid & 7) * 4;
        ushort4 o;
        o.x = __builtin_bit_cast(u16, (_Float16)tile[c][q + 0]);
        o.y = __builtin_bit_cast(u16, (_Float16)tile[c][q + 1]);
        o.z = __builtin_bit_cast(u16, (_Float16)tile[c][q + 2]);
        o.w = __builtin_bit_cast(u16, (_Float16)tile[c][q + 3]);
        *(ushort4*)(outp + (size_t)(c0 + c) * R + r0 + q) = o;
    }
}

// ---------- precompute: Qt[8192][2048] f16 = (P[2048][640] @ Wm[640][8192])^T ----------
__global__ void __launch_bounds__(256) qgemm(const float* __restrict__ P,
    const u16* __restrict__ WH, const u16* __restrict__ WL,
    u16* __restrict__ Qt) {
    const int tid = threadIdx.x;
    const int wid = tid >> 6, lane = tid & 63;
    const int n = lane & 31, kg = lane >> 5;
    const int tile = blockIdx.x * 4 + wid;
    const int ct = tile & 255, kt = tile >> 8;
    const int col = ct * 32 + n;
    const int krow = kt * 32 + n;

    f32x16 acc;
    #pragma unroll
    for (int r = 0; r < 16; ++r) acc[r] = 0.f;

    const float* ap = P + (size_t)krow * 640 + kg * 8;
    const u16* bhp = WH + (size_t)col * 1280 + 640 + kg * 8;
    const u16* blp = WL + (size_t)col * 1280 + 640 + kg * 8;
    #pragma unroll 4
    for (int ks = 0; ks < 40; ++ks) {
        float4 v0 = *(const float4*)(ap + ks * 16);
        float4 v1 = *(const float4*)(ap + ks * 16 + 4);
        float f[8] = {v0.x, v0.y, v0.z, v0.w, v1.x, v1.y, v1.z, v1.w};
        s16x8 ah, al;
        split8(f, ah, al);
        s16x8 bh = *(const s16x8*)(bhp + ks * 16);
        s16x8 bl = *(const s16x8*)(blp + ks * 16);
        acc = __builtin_amdgcn_mfma_f32_32x32x16_bf16(ah, bh, acc, 0, 0, 0);
        acc = __builtin_amdgcn_mfma_f32_32x32x16_bf16(ah, bl, acc, 0, 0, 0);
        acc = __builtin_amdgcn_mfma_f32_32x32x16_bf16(al, bh, acc, 0, 0, 0);
    }
    u16* qrow = Qt + (size_t)col * 2048 + kt * 32 + 4 * kg;
    #pragma unroll
    for (int q = 0; q < 4; ++q) {
        ushort4 o;
        o.x = __builtin_bit_cast(u16, (_Float16)acc[4 * q + 0]);
        o.y = __builtin_bit_cast(u16, (_Float16)acc[4 * q + 1]);
        o.z = __builtin_bit_cast(u16, (_Float16)acc[4 * q + 2]);
        o.w = __builtin_bit_cast(u16, (_Float16)acc[4 * q + 3]);
        *(ushort4*)(qrow + 8 * q) = o;
    }
}

// ---------- main persistent kernel: cross-layer pipeline, one barrier/step ----------
// grid = 256 exactly; __launch_bounds__(512,2) -> 1 block/CU, VGPR budget 256.
__global__ void __launch_bounds__(NTHR, 2) lstm_pipe(
    const float* __restrict__ x,
    const float* __restrict__ bias0, const float* __restrict__ bias1,
    const u16* __restrict__ WH0, const u16* __restrict__ WL0,
    const u16* __restrict__ WH1, const u16* __restrict__ WL1,
    const u16* __restrict__ Qt0, const u16* __restrict__ Qt1,
    const u16* __restrict__ Pt0, const u16* __restrict__ Pt1,
    u16* __restrict__ hb0, u16* __restrict__ hb1,   // [2][32][2048] f16 each
    float* __restrict__ m0r,                        // [2][32][640] f32 ring
    float* out, unsigned* arr) {
    __shared__ float part[8][64][20];
    __shared__ float zb0[32][33];
    __shared__ float zb1[32][33];
    __shared__ u16 hst0[32][8];
    __shared__ u16 hst1[32][8];

    const int tid = threadIdx.x, bid = blockIdx.x;
    const int wid = tid >> 6, lane = tid & 63;
    const int n = lane & 31, kg = lane >> 5;

    const int colmap = (n >> 3) * 2048 + bid * 8 + (n & 7);
    const size_t wOffX = (size_t)colmap * 1280 + wid * 80 + kg * 8;   // Wx k-slice
    const size_t qOff  = (size_t)colmap * 2048 + wid * 256 + kg * 8;  // Qt slice
    const size_t aX0   = (size_t)n * (256 * 640) + wid * 80 + kg * 8; // x row n, +t*640
    const size_t aM0   = (size_t)n * 640 + wid * 80 + kg * 8;         // m0 row n
    const size_t hROff = (size_t)n * 2048 + wid * 256 + kg * 8;       // h frag base

    // D layout: col=lane&31, row=(reg&3)+8*(reg>>2)+4*(lane>>5)
    const int rn = tid >> 4, rm0 = (tid & 15) * 2;
    const int ch = tid >> 5, cb = tid & 31;   // cell mapping (tid<256)

    const bool isL0t = bid < 40;
    const int  l0tb  = (bid < 20) ? bid : bid - 20;
    const int  l0par = (bid < 20) ? 0 : 1;
    const bool isL1t = (bid >= 40 && bid < 80);
    const int  l1tb  = (bid < 60) ? bid - 40 : bid - 60;
    const int  l1par = (bid < 60) ? 0 : 1;
    const size_t p0Off = (size_t)(l0tb * 32 + n) * 2048 + wid * 256 + kg * 8;
    const size_t p1Off = (size_t)(l1tb * 32 + n) * 2048 + wid * 256 + kg * 8;

    const float bv0 = bias0[(rn >> 3) * 2048 + bid * 8 + (rn & 7)];
    const float bv1 = bias1[(rn >> 3) * 2048 + bid * 8 + (rn & 7)];

    // both layers' Q fragments register-resident (128 VGPRs)
    f16x8 qf0[16], qf1[16];
    #pragma unroll
    for (int ks = 0; ks < 16; ++ks) {
        qf0[ks] = *(const f16x8*)(Qt0 + qOff + ks * 16);
        qf1[ks] = *(const f16x8*)(Qt1 + qOff + ks * 16);
    }

    float creg0 = 0.f, creg1 = 0.f;

    auto xp0 = [&](int t) -> f32x16 {   // x(t) @ Wx0, plain cached loads
        f32x16 a;
        #pragma unroll
        for (int r = 0; r < 16; ++r) a[r] = 0.f;
        const float* xb = x + aX0 + (size_t)t * 640;
        const u16* whx = WH0 + wOffX;
        const u16* wlx = WL0 + wOffX;
        #pragma unroll
        for (int ks = 0; ks < 5; ++ks) {
            float4 v0 = *(const float4*)(xb + ks * 16);
            float4 v1 = *(const float4*)(xb + ks * 16 + 4);
            float f[8] = {v0.x, v0.y, v0.z, v0.w, v1.x, v1.y, v1.z, v1.w};
            s16x8 ah, al;
            split8(f, ah, al);
            s16x8 bh = *(const s16x8*)(whx + ks * 16);
            s16x8 bl = *(const s16x8*)(wlx + ks * 16);
            a = __builtin_amdgcn_mfma_f32_32x32x16_bf16(ah, bh, a, 0, 0, 0);
            a = __builtin_amdgcn_mfma_f32_32x32x16_bf16(ah, bl, a, 0, 0, 0);
            a = __builtin_amdgcn_mfma_f32_32x32x16_bf16(al, bh, a, 0, 0, 0);
        }
        return a;
    };
    auto xp1 = [&](int s) -> f32x16 {   // m0(s) @ Wx1, agent loads
        f32x16 a;
        #pragma unroll
        for (int r = 0; r < 16; ++r) a[r] = 0.f;
        const float* mb = m0r + (size_t)(s & 1) * MSZ + aM0;
        const u16* whx = WH1 + wOffX;
        const u16* wlx = WL1 + wOffX;
        #pragma unroll
        for (int ks = 0; ks < 5; ++ks) {
            float f[8];
            ld8f(mb + ks * 16, f);
            s16x8 ah, al;
            split8(f, ah, al);
            s16x8 bh = *(const s16x8*)(whx + ks * 16);
            s16x8 bl = *(const s16x8*)(wlx + ks * 16);
            a = __builtin_amdgcn_mfma_f32_32x32x16_bf16(ah, bh, a, 0, 0, 0);
            a = __builtin_amdgcn_mfma_f32_32x32x16_bf16(ah, bl, a, 0, 0, 0);
            a = __builtin_amdgcn_mfma_f32_32x32x16_bf16(al, bh, a, 0, 0, 0);
        }
        return a;
    };
    auto stash = [&](const f32x16& v) {   // acc -> part (caller syncs around)
        #pragma unroll
        for (int r = 0; r < 4; ++r) {
            float4 w;
            w.x = v[4 * r + 0]; w.y = v[4 * r + 1];
            w.z = v[4 * r + 2]; w.w = v[4 * r + 3];
            *(float4*)&part[wid][lane][4 * r] = w;
        }
    };
    auto sum8 = [&](int m) -> float {
        int lp = rn + 32 * ((m >> 2) & 1);
        int rg = (m & 3) + 4 * (m >> 3);
        float s = 0.f;
        #pragma unroll
        for (int w = 0; w < 8; ++w) s += part[w][lp][rg];
        return s;
    };

    f32x16 zacc0 = xp0(0);

    for (int g = 0; g <= 257; ++g) {
        if (g > 0) pollall(arr, (unsigned)g);   // everything of step g-1 visible
        const int s = g - 2;
        const bool doL0 = (g <= 255);
        const bool doL1 = (s >= 0);
        const bool l0p  = isL0t && g >= 1 && g <= 255 && (((g - 1) & 1) == l0par);
        const bool l0pT = isL0t && g == 256 && (((g - 1) & 1) == l0par);
        const bool l1p  = isL1t && s >= 1 && (((s - 1) & 1) == l1par);

        f32x16 pacc0, pacc1;

        // ===================== layer 0 gate =====================
        if (doL0) {
            f32x16 acc0 = zacc0;
            if (l0p) {
                #pragma unroll
                for (int r = 0; r < 16; ++r) pacc0[r] = 0.f;
            }
            if (g >= 1) {
                const u16* hc = hb0 + (size_t)((g - 1) & 1) * HSZ2 + hROff;
                const u16* pf = Pt0 + p0Off;
                if (l0p) {
                    #pragma unroll
                    for (int ks = 0; ks < 16; ++ks) {
                        f16x8 a = ald_f16x8(hc + ks * 16);
                        acc0  = __builtin_amdgcn_mfma_f32_32x32x16_f16(a, qf0[ks], acc0, 0, 0, 0);
                        pacc0 = __builtin_amdgcn_mfma_f32_32x32x16_f16(a, *(const f16x8*)(pf + ks * 16), pacc0, 0, 0, 0);
                    }
                } else {
                    #pragma unroll
                    for (int ks = 0; ks < 16; ++ks)
                        acc0 = __builtin_amdgcn_mfma_f32_32x32x16_f16(ald_f16x8(hc + ks * 16), qf0[ks], acc0, 0, 0, 0);
                }
            }
            stash(acc0);
            __syncthreads();
            #pragma unroll
            for (int j = 0; j < 2; ++j) { int m = rm0 + j; zb0[rn][m] = sum8(m) + bv0; }
            __syncthreads();
            if (tid < 256) {   // cell0 (gate order i, j, f, o)
                float zi = zb0[0 * 8 + ch][cb];
                float zj = zb0[1 * 8 + ch][cb];
                float zf = zb0[2 * 8 + ch][cb];
                float zo = zb0[3 * 8 + ch][cb];
                float cn = sigm(zf + 1.0f) * creg0 + sigm(zi) * tanhf(zj);
                creg0 = cn;
                hst0[cb][ch] = __builtin_bit_cast(u16, (_Float16)(sigm(zo) * tanhf(cn)));
            }
        }

        // ===================== layer 0 proj -> m0 ring =====================
        if (l0pT) {   // standalone tail proj of h0(255) at g=256
            #pragma unroll
            for (int r = 0; r < 16; ++r) pacc0[r] = 0.f;
            const u16* hc = hb0 + (size_t)(255 & 1) * HSZ2 + hROff;
            const u16* pf = Pt0 + p0Off;
            #pragma unroll
            for (int ks = 0; ks < 16; ++ks)
                pacc0 = __builtin_amdgcn_mfma_f32_32x32x16_f16(ald_f16x8(hc + ks * 16), *(const f16x8*)(pf + ks * 16), pacc0, 0, 0, 0);
        }
        if (l0p || l0pT) {
            __syncthreads();
            stash(pacc0);
            __syncthreads();
            const int mi = g - 1;
            float* mrow = m0r + (size_t)(mi & 1) * MSZ;
            #pragma unroll
            for (int j = 0; j < 2; ++j) {
                int m = rm0 + j;
                ast32(mrow + (size_t)m * 640 + l0tb * 32 + rn, sum8(m));
            }
        }

        // ===================== layer 1 gate (s = g-2) =====================
        if (doL1) {
            f32x16 acc1 = xp1(s);
            if (l1p) {
                #pragma unroll
                for (int r = 0; r < 16; ++r) pacc1[r] = 0.f;
            }
            if (s >= 1) {
                const u16* hc = hb1 + (size_t)((s - 1) & 1) * HSZ2 + hROff;
                const u16* pf = Pt1 + p1Off;
                if (l1p) {
                    #pragma unroll
                    for (int ks = 0; ks < 16; ++ks) {
                        f16x8 a = ald_f16x8(hc + ks * 16);
                        acc1  = __builtin_amdgcn_mfma_f32_32x32x16_f16(a, qf1[ks], acc1, 0, 0, 0);
                        pacc1 = __builtin_amdgcn_mfma_f32_32x32x16_f16(a, *(const f16x8*)(pf + ks * 16), pacc1, 0, 0, 0);
                    }
                } else {
                    #pragma unroll
                    for (int ks = 0; ks < 16; ++ks)
                        acc1 = __builtin_amdgcn_mfma_f32_32x32x16_f16(ald_f16x8(hc + ks * 16), qf1[ks], acc1, 0, 0, 0);
                }
            }
            __syncthreads();    // part free
            stash(acc1);
            __syncthreads();
            #pragma unroll
            for (int j = 0; j < 2; ++j) { int m = rm0 + j; zb1[rn][m] = sum8(m) + bv1; }
            __syncthreads();
            if (tid < 256) {   // cell1
                float zi = zb1[0 * 8 + ch][cb];
                float zj = zb1[1 * 8 + ch][cb];
                float zf = zb1[2 * 8 + ch][cb];
                float zo = zb1[3 * 8 + ch][cb];
                float cn = sigm(zf + 1.0f) * creg1 + sigm(zi) * tanhf(zj);
                creg1 = cn;
                hst1[cb][ch] = __builtin_bit_cast(u16, (_Float16)(sigm(zo) * tanhf(cn)));
            }
        }

        // ===================== publish + arrive =====================
        __syncthreads();
        if (doL0 && wid == 0) {
            int b = tid >> 1, hf = tid & 1;
            u64 v = *(const u64*)&hst0[b][hf * 4];
            ast64(hb0 + (size_t)(g & 1) * HSZ2 + (size_t)b * 2048 + bid * 8 + hf * 4, v);
        }
        if (doL1 && wid == 1) {
            int l = tid - 64;
            int b = l >> 1, hf = l & 1;
            u64 v = *(const u64*)&hst1[b][hf * 4];
            ast64(hb1 + (size_t)(s & 1) * HSZ2 + (size_t)b * 2048 + bid * 8 + hf * 4, v);
        }
        __syncthreads();   // drains every wave's stores (h0, h1, m0) before flag
        if (tid == 0)
            __hip_atomic_store(arr + bid, (unsigned)(g + 1), __ATOMIC_RELAXED, __HIP_MEMORY_SCOPE_AGENT);

        // ===================== post-arrive (off critical path) =====================
        if (l1p) {   // final output rows for t = s-1 (plain stores; host-read only)
            __syncthreads();
            stash(pacc1);
            __syncthreads();
            #pragma unroll
            for (int j = 0; j < 2; ++j) {
                int m = rm0 + j;
                out[((size_t)m * 256 + (s - 1)) * 640 + l1tb * 32 + rn] = sum8(m);
            }
        }
        if (g < 255) zacc0 = xp0(g + 1);
    }

    // tail: project h1(255) -> out t=255 (parity-1 teams: blocks 60..79)
    if (isL1t && l1par == 1) {
        pollall(arr, 258u);
        f32x16 pacc;
        #pragma unroll
        for (int r = 0; r < 16; ++r) pacc[r] = 0.f;
        const u16* hc = hb1 + (size_t)(255 & 1) * HSZ2 + hROff;
        const u16* pf = Pt1 + p1Off;
        #pragma unroll
        for (int ks = 0; ks < 16; ++ks)
            pacc = __builtin_amdgcn_mfma_f32_32x32x16_f16(ald_f16x8(hc + ks * 16), *(const f16x8*)(pf + ks * 16), pacc, 0, 0, 0);
        stash(pacc);
        __syncthreads();
        #pragma unroll
        for (int j = 0; j < 2; ++j) {
            int m = rm0 + j;
            out[((size_t)m * 256 + 255) * 640 + l1tb * 32 + rn] = sum8(m);
        }
    }
}

// ---------- fallback (R1-style) if ws too small ----------
__device__ __forceinline__ void grid_bar_slow(unsigned int* bar, unsigned int& epoch) {
    __syncthreads();
    epoch++;
    if (threadIdx.x == 0) {
        __threadfence();
        atomicAdd(bar, 1u);
        const unsigned int target = epoch * NBLK;
        while (__hip_atomic_load(bar, __ATOMIC_RELAXED, __HIP_MEMORY_SCOPE_AGENT) < target)
            __builtin_amdgcn_s_sleep(1);
        __threadfence();
    }
    __syncthreads();
}

__global__ void __launch_bounds__(NTHR, 1) lstm_fb(
    const float* __restrict__ x,
    const float* __restrict__ W0, const float* __restrict__ b0, const float* __restrict__ Pr0,
    const float* __restrict__ W1, const float* __restrict__ b1, const float* __restrict__ Pr1,
    float* out, float* ws) {
    const int tid = threadIdx.x;
    const int bid = blockIdx.x;
    unsigned int* bar = (unsigned int*)ws;
    float* mbuf0 = ws + 1024;
    float* mbuf1 = mbuf0 + 32 * 640;
    float* hws = mbuf1 + 32 * 640;
    __shared__ float zbuf[32 * 33];
    __shared__ float pred[512];
    unsigned int epoch = 0;
    const int c_idx = tid & 31;
    const int bg = tid >> 5;
    const int b0r = bg * 2;
    const int col = (c_idx >> 3) * 2048 + bid * 8 + (c_idx & 7);
    const int ch = tid >> 5;
    const int cb = tid & 31;
    const int p_s = (bid * 640) / NBLK;
    const int p_e = ((bid + 1) * 640) / NBLK;
    const int np = p_e - p_s;
    const int kq_n = (np == 2) ? 8 : 4;
    const int klen = 2048 / kq_n;
    const int pg = tid >> 5;
    const bool pact = pg < np * kq_n;
    const int pj = pact ? (pg % np) : 0;
    const int kq = pact ? (pg / np) : 0;
    for (int layer = 0; layer < 2; ++layer) {
        const float* W = layer ? W1 : W0;
        const float* bbv = layer ? b1 : b0;
        const float* Pr = layer ? Pr1 : Pr0;
        const float* inb = layer ? (const float*)out : x;
        for (int i = bid * NTHR + tid; i < 32 * 640; i += NBLK * NTHR) mbuf0[i] = 0.0f;
        float creg = 0.0f;
        grid_bar_slow(bar, epoch);
        const float bias = bbv[col];
        for (int t = 0; t < 256; ++t) {
            float* mcur = (t & 1) ? mbuf1 : mbuf0;
            float* mnxt = (t & 1) ? mbuf0 : mbuf1;
            const float* in0 = inb + (size_t)(b0r * 256 + t) * 640;
            const float* in1 = in0 + (size_t)256 * 640;
            const float* wp = W + col;
            float a0 = 0.f, a1 = 0.f;
            #pragma unroll 4
            for (int k = 0; k < 640; k += 4) {
                float4 u0 = *(const float4*)(in0 + k);
                float4 u1 = *(const float4*)(in1 + k);
                float w0 = wp[(size_t)(k + 0) * 8192], w1 = wp[(size_t)(k + 1) * 8192];
                float w2 = wp[(size_t)(k + 2) * 8192], w3 = wp[(size_t)(k + 3) * 8192];
                a0 += w0 * u0.x + w1 * u0.y + w2 * u0.z + w3 * u0.w;
                a1 += w0 * u1.x + w1 * u1.y + w2 * u1.z + w3 * u1.w;
            }
            const float* q0 = mcur + (size_t)b0r * 640;
            const float* q1 = q0 + 640;
            #pragma unroll 4
            for (int k = 0; k < 640; k += 4) {
                float4 u0 = *(const float4*)(q0 + k);
                float4 u1 = *(const float4*)(q1 + k);
                float w0 = wp[(size_t)(640 + k + 0) * 8192], w1 = wp[(size_t)(640 + k + 1) * 8192];
                float w2 = wp[(size_t)(640 + k + 2) * 8192], w3 = wp[(size_t)(640 + k + 3) * 8192];
                a0 += w0 * u0.x + w1 * u0.y + w2 * u0.z + w3 * u0.w;
                a1 += w0 * u1.x + w1 * u1.y + w2 * u1.z + w3 * u1.w;
            }
            zbuf[c_idx * 33 + b0r + 0] = a0 + bias;
            zbuf[c_idx * 33 + b0r + 1] = a1 + bias;
            __syncthreads();
            if (tid < 256) {
                float zi = zbuf[(0 * 8 + ch) * 33 + cb];
                float zj = zbuf[(1 * 8 + ch) * 33 + cb];
                float zf = zbuf[(2 * 8 + ch) * 33 + cb];
                float zo = zbuf[(3 * 8 + ch) * 33 + cb];
                float cn = sigm(zf + 1.0f) * creg + sigm(zi) * tanhf(zj);
                creg = cn;
                hws[(size_t)(bid * 8 + ch) * 32 + cb] = sigm(zo) * tanhf(cn);
            }
            grid_bar_slow(bar, epoch);
            if (pact) {
                const int p = p_s + pj;
                const float* pp = Pr + p;
                const int k0 = kq * klen;
                float s = 0.f;
                #pragma unroll 4
                for (int k = k0; k < k0 + klen; ++k) s += hws[(size_t)k * 32 + cb] * pp[(size_t)k * 640];
                pred[(pj * 32 + cb) * kq_n + kq] = s;
            }
            __syncthreads();
            if (tid < np * 32) {
                float s = 0.f;
                for (int q2 = 0; q2 < kq_n; ++q2) s += pred[tid * kq_n + q2];
                const int p = p_s + (tid >> 5);
                const int b = tid & 31;
                mnxt[(size_t)b * 640 + p] = s;
                out[((size_t)b * 256 + t) * 640 + p] = s;
            }
            grid_bar_slow(bar, epoch);
        }
    }
}

extern "C" void kernel_launch(void* const* d_in, const int* in_sizes, int n_in,
                              void* d_out, int out_size, void* d_ws, size_t ws_size,
                              hipStream_t stream) {
    const float* x   = (const float*)d_in[0];
    const float* W0  = (const float*)d_in[1];
    const float* b0  = (const float*)d_in[2];
    const float* P0  = (const float*)d_in[3];
    const float* W1  = (const float*)d_in[4];
    const float* b1  = (const float*)d_in[5];
    const float* P1  = (const float*)d_in[6];
    float* out = (float*)d_out;

    // ws layout (bytes, 256-aligned chunks)
    size_t off = 0;
    auto alloc = [&](size_t bytes) { size_t o = off; off += (bytes + 255) & ~(size_t)255; return o; };
    const size_t oBar = alloc(32768);             // arr[256] compact
    const size_t szW  = (size_t)8192 * 1280 * 2;  // Wt bf16 plane
    const size_t szQ  = (size_t)8192 * 2048 * 2;  // Qt f16
    const size_t szPt = (size_t)640 * 2048 * 2;   // Pt f16
    const size_t oWH0 = alloc(szW), oWL0 = alloc(szW), oWH1 = alloc(szW), oWL1 = alloc(szW);
    const size_t oQt0 = alloc(szQ), oQt1 = alloc(szQ);
    const size_t oPt0 = alloc(szPt), oPt1 = alloc(szPt);
    const size_t oH0  = alloc((size_t)2 * HSZ2 * 2);
    const size_t oH1  = alloc((size_t)2 * HSZ2 * 2);
    const size_t oM0  = alloc((size_t)2 * MSZ * 4);
    const size_t need = off;

    hipMemsetAsync(d_ws, 0, 32768, stream);  // barrier flags start at 0 every call

    if (ws_size < need) {  // fallback path (~0.5 MB ws)
        float* ws = (float*)d_ws;
        void* args[] = {(void*)&x, (void*)&W0, (void*)&b0, (void*)&P0,
                        (void*)&W1, (void*)&b1, (void*)&P1, (void*)&out, (void*)&ws};
        hipError_t err = hipLaunchCooperativeKernel((const void*)lstm_fb,
                                                    dim3(NBLK), dim3(NTHR), args, 0, stream);
        if (err != hipSuccess)
            lstm_fb<<<dim3(NBLK), dim3(NTHR), 0, stream>>>(x, W0, b0, P0, W1, b1, P1, out, ws);
        return;
    }

    char* w = (char*)d_ws;
    u16 *WH0p = (u16*)(w + oWH0), *WL0p = (u16*)(w + oWL0);
    u16 *WH1p = (u16*)(w + oWH1), *WL1p = (u16*)(w + oWL1);
    u16 *Qt0p = (u16*)(w + oQt0), *Qt1p = (u16*)(w + oQt1);
    u16 *Pt0p = (u16*)(w + oPt0), *Pt1p = (u16*)(w + oPt1);
    u16 *hb0p = (u16*)(w + oH0), *hb1p = (u16*)(w + oH1);
    float* m0rp = (float*)(w + oM0);
    unsigned* arrp = (unsigned*)(w + oBar);

    // precompute: weight transposes + Q = P @ Wm (inside the graph, every call)
    transpose_split<<<dim3(256, 40), 256, 0, stream>>>(W0, WH0p, WL0p, 1280, 8192);
    transpose_split<<<dim3(256, 40), 256, 0, stream>>>(W1, WH1p, WL1p, 1280, 8192);
    transpose_f16<<<dim3(20, 64), 256, 0, stream>>>(P0, Pt0p, 2048, 640);
    transpose_f16<<<dim3(20, 64), 256, 0, stream>>>(P1, Pt1p, 2048, 640);
    qgemm<<<dim3(4096), 256, 0, stream>>>(P0, WH0p, WL0p, Qt0p);
    qgemm<<<dim3(4096), 256, 0, stream>>>(P1, WH1p, WL1p, Qt1p);

    const float *b0c = b0, *b1c = b1;
    void* args[] = {(void*)&x, (void*)&b0c, (void*)&b1c,
                    (void*)&WH0p, (void*)&WL0p, (void*)&WH1p, (void*)&WL1p,
                    (void*)&Qt0p, (void*)&Qt1p, (void*)&Pt0p, (void*)&Pt1p,
                    (void*)&hb0p, (void*)&hb1p, (void*)&m0rp,
                    (void*)&out, (void*)&arrp};
    hipError_t err = hipLaunchCooperativeKernel((const void*)lstm_pipe,
                                                dim3(NBLK), dim3(NTHR), args, 0, stream);
    if (err != hipSuccess)
        lstm_pipe<<<dim3(NBLK), dim3(NTHR), 0, stream>>>(
            x, b0c, b1c, WH0p, WL0p, WH1p, WL1p, Qt0p, Qt1p, Pt0p, Pt1p,
            hb0p, hb1p, m0rp, out, arrp);
}

// Round 9
// 7216.756 us; speedup vs baseline: 11.4401x; 1.4470x over previous
//
#include <hip/hip_runtime.h>
#include <math.h>

typedef __attribute__((ext_vector_type(8))) short s16x8;
typedef __attribute__((ext_vector_type(8))) _Float16 f16x8;
typedef __attribute__((ext_vector_type(16))) float f32x16;
typedef unsigned long long u64;
typedef unsigned short u16;

#define NBLK 256
#define NTHR 512

constexpr int HSZ2 = 32 * 2048;  // one h slot, f16 elems
constexpr int MSZ  = 32 * 640;   // one m0 slot, f32 elems

__device__ __forceinline__ float sigm(float v) { return 1.0f / (1.0f + expf(-v)); }

__device__ __forceinline__ unsigned short bf16_rne(float x) {
    unsigned u = __float_as_uint(x);
    return (unsigned short)((u + 0x7FFFu + ((u >> 16) & 1u)) >> 16);
}
__device__ __forceinline__ void split2(float x, unsigned short& hi, unsigned short& lo) {
    unsigned u = __float_as_uint(x);
    hi = (unsigned short)(u >> 16);
    float hf = __uint_as_float(u & 0xFFFF0000u);
    lo = bf16_rne(x - hf);
}
__device__ __forceinline__ void split8(const float* f, s16x8& h, s16x8& l) {
    #pragma unroll
    for (int i = 0; i < 8; ++i) {
        unsigned short hh, ll;
        split2(f[i], hh, ll);
        h[i] = (short)hh; l[i] = (short)ll;
    }
}

// ---- agent-scope stores (publish path; readers use plain cached loads) ----
__device__ __forceinline__ void ast64(u16* p, u64 v) {
    __hip_atomic_store((u64*)p, v, __ATOMIC_RELAXED, __HIP_MEMORY_SCOPE_AGENT);
}
__device__ __forceinline__ void ast32(float* p, float v) {
    __hip_atomic_store((unsigned*)p, __float_as_uint(v), __ATOMIC_RELAXED, __HIP_MEMORY_SCOPE_AGENT);
}

// ---- all-poll barrier ----
__device__ __forceinline__ void pollall(const unsigned* arr, unsigned e) {
    if (threadIdx.x < 64) {
        const int i0 = (int)threadIdx.x * 4;
        for (;;) {
            bool ok = (__hip_atomic_load(arr + i0 + 0, __ATOMIC_RELAXED, __HIP_MEMORY_SCOPE_AGENT) >= e) &&
                      (__hip_atomic_load(arr + i0 + 1, __ATOMIC_RELAXED, __HIP_MEMORY_SCOPE_AGENT) >= e) &&
                      (__hip_atomic_load(arr + i0 + 2, __ATOMIC_RELAXED, __HIP_MEMORY_SCOPE_AGENT) >= e) &&
                      (__hip_atomic_load(arr + i0 + 3, __ATOMIC_RELAXED, __HIP_MEMORY_SCOPE_AGENT) >= e);
            if (__all(ok)) break;
            __builtin_amdgcn_s_sleep(1);
        }
    }
    __syncthreads();
}

// ---------- precompute: transpose [R][C] fp32 -> [C][R] bf16 hi/lo ----------
__global__ void transpose_split(const float* __restrict__ in,
                                u16* __restrict__ outHi, u16* __restrict__ outLo,
                                int R, int C) {
    __shared__ float tile[32][33];
    const int c0 = blockIdx.x * 32, r0 = blockIdx.y * 32;
    const int tid = threadIdx.x;  // 256
    {
        int r = tid >> 3, q = (tid & 7) * 4;
        float4 v = *(const float4*)(in + (size_t)(r0 + r) * C + c0 + q);
        tile[q + 0][r] = v.x; tile[q + 1][r] = v.y;
        tile[q + 2][r] = v.z; tile[q + 3][r] = v.w;
    }
    __syncthreads();
    {
        int c = tid >> 3, q = (tid & 7) * 4;
        ushort4 h, l;
        unsigned short hh, ll;
        split2(tile[c][q + 0], hh, ll); h.x = hh; l.x = ll;
        split2(tile[c][q + 1], hh, ll); h.y = hh; l.y = ll;
        split2(tile[c][q + 2], hh, ll); h.z = hh; l.z = ll;
        split2(tile[c][q + 3], hh, ll); h.w = hh; l.w = ll;
        size_t o = (size_t)(c0 + c) * R + r0 + q;
        *(ushort4*)(outHi + o) = h;
        *(ushort4*)(outLo + o) = l;
    }
}

// ---------- precompute: transpose [R][C] fp32 -> [C][R] f16 ----------
__global__ void transpose_f16(const float* __restrict__ in, u16* __restrict__ outp,
                              int R, int C) {
    __shared__ float tile[32][33];
    const int c0 = blockIdx.x * 32, r0 = blockIdx.y * 32;
    const int tid = threadIdx.x;  // 256
    {
        int r = tid >> 3, q = (tid & 7) * 4;
        float4 v = *(const float4*)(in + (size_t)(r0 + r) * C + c0 + q);
        tile[q + 0][r] = v.x; tile[q + 1][r] = v.y;
        tile[q + 2][r] = v.z; tile[q + 3][r] = v.w;
    }
    __syncthreads();
    {
        int c = tid >> 3, q = (tid & 7) * 4;
        ushort4 o;
        o.x = __builtin_bit_cast(u16, (_Float16)tile[c][q + 0]);
        o.y = __builtin_bit_cast(u16, (_Float16)tile[c][q + 1]);
        o.z = __builtin_bit_cast(u16, (_Float16)tile[c][q + 2]);
        o.w = __builtin_bit_cast(u16, (_Float16)tile[c][q + 3]);
        *(ushort4*)(outp + (size_t)(c0 + c) * R + r0 + q) = o;
    }
}

// ---------- precompute: Qt[8192][2048] f16 = (P[2048][640] @ Wm[640][8192])^T ----------
__global__ void __launch_bounds__(256) qgemm(const float* __restrict__ P,
    const u16* __restrict__ WH, const u16* __restrict__ WL,
    u16* __restrict__ Qt) {
    const int tid = threadIdx.x;
    const int wid = tid >> 6, lane = tid & 63;
    const int n = lane & 31, kg = lane >> 5;
    const int tile = blockIdx.x * 4 + wid;
    const int ct = tile & 255, kt = tile >> 8;
    const int col = ct * 32 + n;
    const int krow = kt * 32 + n;

    f32x16 acc;
    #pragma unroll
    for (int r = 0; r < 16; ++r) acc[r] = 0.f;

    const float* ap = P + (size_t)krow * 640 + kg * 8;
    const u16* bhp = WH + (size_t)col * 1280 + 640 + kg * 8;
    const u16* blp = WL + (size_t)col * 1280 + 640 + kg * 8;
    #pragma unroll 4
    for (int ks = 0; ks < 40; ++ks) {
        float4 v0 = *(const float4*)(ap + ks * 16);
        float4 v1 = *(const float4*)(ap + ks * 16 + 4);
        float f[8] = {v0.x, v0.y, v0.z, v0.w, v1.x, v1.y, v1.z, v1.w};
        s16x8 ah, al;
        split8(f, ah, al);
        s16x8 bh = *(const s16x8*)(bhp + ks * 16);
        s16x8 bl = *(const s16x8*)(blp + ks * 16);
        acc = __builtin_amdgcn_mfma_f32_32x32x16_bf16(ah, bh, acc, 0, 0, 0);
        acc = __builtin_amdgcn_mfma_f32_32x32x16_bf16(ah, bl, acc, 0, 0, 0);
        acc = __builtin_amdgcn_mfma_f32_32x32x16_bf16(al, bh, acc, 0, 0, 0);
    }
    u16* qrow = Qt + (size_t)col * 2048 + kt * 32 + 4 * kg;
    #pragma unroll
    for (int q = 0; q < 4; ++q) {
        ushort4 o;
        o.x = __builtin_bit_cast(u16, (_Float16)acc[4 * q + 0]);
        o.y = __builtin_bit_cast(u16, (_Float16)acc[4 * q + 1]);
        o.z = __builtin_bit_cast(u16, (_Float16)acc[4 * q + 2]);
        o.w = __builtin_bit_cast(u16, (_Float16)acc[4 * q + 3]);
        *(ushort4*)(qrow + 8 * q) = o;
    }
}

// ---------- main persistent kernel: cross-layer pipeline, one barrier/step ----------
// Cross-block data now flows through NO-REUSE rings (one slot per timestep):
// writers publish with sc1 agent stores; readers use PLAIN cached loads.
// Fresh-by-construction: L1/L2 invalidated at dispatch, each slot address is
// touched exactly once (read after the barrier that orders the writer's store).
// This lets the 32 blocks of an XCD share the h broadcast through their L2
// (R8 was HBM-bound at 888 GB/s on per-block agent-scope reads).
__global__ void __launch_bounds__(NTHR, 2) lstm_pipe(
    const float* __restrict__ x,
    const float* __restrict__ bias0, const float* __restrict__ bias1,
    const u16* __restrict__ WH0, const u16* __restrict__ WL0,
    const u16* __restrict__ WH1, const u16* __restrict__ WL1,
    const u16* __restrict__ Qt0, const u16* __restrict__ Qt1,
    const u16* __restrict__ Pt0, const u16* __restrict__ Pt1,
    u16* __restrict__ hb0, u16* __restrict__ hb1,   // [256][32][2048] f16 each
    float* __restrict__ m0r,                        // [256][32][640] f32
    float* out, unsigned* arr) {
    __shared__ float part[8][64][20];
    __shared__ float zb0[32][33];
    __shared__ float zb1[32][33];
    __shared__ u16 hst0[32][8];
    __shared__ u16 hst1[32][8];

    const int tid = threadIdx.x, bid = blockIdx.x;
    const int wid = tid >> 6, lane = tid & 63;
    const int n = lane & 31, kg = lane >> 5;

    const int colmap = (n >> 3) * 2048 + bid * 8 + (n & 7);
    const size_t wOffX = (size_t)colmap * 1280 + wid * 80 + kg * 8;   // Wx k-slice
    const size_t qOff  = (size_t)colmap * 2048 + wid * 256 + kg * 8;  // Qt slice
    const size_t aX0   = (size_t)n * (256 * 640) + wid * 80 + kg * 8; // x row n, +t*640
    const size_t aM0   = (size_t)n * 640 + wid * 80 + kg * 8;         // m0 row n
    const size_t hROff = (size_t)n * 2048 + wid * 256 + kg * 8;       // h frag base

    // D layout: col=lane&31, row=(reg&3)+8*(reg>>2)+4*(lane>>5)
    const int rn = tid >> 4, rm0 = (tid & 15) * 2;
    const int ch = tid >> 5, cb = tid & 31;   // cell mapping (tid<256)

    const bool isL0t = bid < 40;
    const int  l0tb  = (bid < 20) ? bid : bid - 20;
    const int  l0par = (bid < 20) ? 0 : 1;
    const bool isL1t = (bid >= 40 && bid < 80);
    const int  l1tb  = (bid < 60) ? bid - 40 : bid - 60;
    const int  l1par = (bid < 60) ? 0 : 1;
    const size_t p0Off = (size_t)(l0tb * 32 + n) * 2048 + wid * 256 + kg * 8;
    const size_t p1Off = (size_t)(l1tb * 32 + n) * 2048 + wid * 256 + kg * 8;

    const float bv0 = bias0[(rn >> 3) * 2048 + bid * 8 + (rn & 7)];
    const float bv1 = bias1[(rn >> 3) * 2048 + bid * 8 + (rn & 7)];

    // both layers' Q fragments register-resident (128 VGPRs)
    f16x8 qf0[16], qf1[16];
    #pragma unroll
    for (int ks = 0; ks < 16; ++ks) {
        qf0[ks] = *(const f16x8*)(Qt0 + qOff + ks * 16);
        qf1[ks] = *(const f16x8*)(Qt1 + qOff + ks * 16);
    }

    float creg0 = 0.f, creg1 = 0.f;

    auto xp0 = [&](int t) -> f32x16 {   // x(t) @ Wx0, plain cached loads
        f32x16 a;
        #pragma unroll
        for (int r = 0; r < 16; ++r) a[r] = 0.f;
        const float* xb = x + aX0 + (size_t)t * 640;
        const u16* whx = WH0 + wOffX;
        const u16* wlx = WL0 + wOffX;
        #pragma unroll
        for (int ks = 0; ks < 5; ++ks) {
            float4 v0 = *(const float4*)(xb + ks * 16);
            float4 v1 = *(const float4*)(xb + ks * 16 + 4);
            float f[8] = {v0.x, v0.y, v0.z, v0.w, v1.x, v1.y, v1.z, v1.w};
            s16x8 ah, al;
            split8(f, ah, al);
            s16x8 bh = *(const s16x8*)(whx + ks * 16);
            s16x8 bl = *(const s16x8*)(wlx + ks * 16);
            a = __builtin_amdgcn_mfma_f32_32x32x16_bf16(ah, bh, a, 0, 0, 0);
            a = __builtin_amdgcn_mfma_f32_32x32x16_bf16(ah, bl, a, 0, 0, 0);
            a = __builtin_amdgcn_mfma_f32_32x32x16_bf16(al, bh, a, 0, 0, 0);
        }
        return a;
    };
    auto xp1 = [&](int s) -> f32x16 {   // m0(s) @ Wx1, plain cached loads (no-reuse slot)
        f32x16 a;
        #pragma unroll
        for (int r = 0; r < 16; ++r) a[r] = 0.f;
        const float* mb = m0r + (size_t)s * MSZ + aM0;
        const u16* whx = WH1 + wOffX;
        const u16* wlx = WL1 + wOffX;
        #pragma unroll
        for (int ks = 0; ks < 5; ++ks) {
            float4 v0 = *(const float4*)(mb + ks * 16);
            float4 v1 = *(const float4*)(mb + ks * 16 + 4);
            float f[8] = {v0.x, v0.y, v0.z, v0.w, v1.x, v1.y, v1.z, v1.w};
            s16x8 ah, al;
            split8(f, ah, al);
            s16x8 bh = *(const s16x8*)(whx + ks * 16);
            s16x8 bl = *(const s16x8*)(wlx + ks * 16);
            a = __builtin_amdgcn_mfma_f32_32x32x16_bf16(ah, bh, a, 0, 0, 0);
            a = __builtin_amdgcn_mfma_f32_32x32x16_bf16(ah, bl, a, 0, 0, 0);
            a = __builtin_amdgcn_mfma_f32_32x32x16_bf16(al, bh, a, 0, 0, 0);
        }
        return a;
    };
    auto stash = [&](const f32x16& v) {   // acc -> part (caller syncs around)
        #pragma unroll
        for (int r = 0; r < 4; ++r) {
            float4 w;
            w.x = v[4 * r + 0]; w.y = v[4 * r + 1];
            w.z = v[4 * r + 2]; w.w = v[4 * r + 3];
            *(float4*)&part[wid][lane][4 * r] = w;
        }
    };
    auto sum8 = [&](int m) -> float {
        int lp = rn + 32 * ((m >> 2) & 1);
        int rg = (m & 3) + 4 * (m >> 3);
        float s = 0.f;
        #pragma unroll
        for (int w = 0; w < 8; ++w) s += part[w][lp][rg];
        return s;
    };

    f32x16 zacc0 = xp0(0);

    for (int g = 0; g <= 257; ++g) {
        if (g > 0) pollall(arr, (unsigned)g);   // everything of step g-1 visible
        const int s = g - 2;
        const bool doL0 = (g <= 255);
        const bool doL1 = (s >= 0);
        const bool l0p  = isL0t && g >= 1 && g <= 255 && (((g - 1) & 1) == l0par);
        const bool l0pT = isL0t && g == 256 && (((g - 1) & 1) == l0par);
        const bool l1p  = isL1t && s >= 1 && (((s - 1) & 1) == l1par);

        f32x16 pacc0, pacc1;

        // ===================== layer 0 gate =====================
        if (doL0) {
            f32x16 acc0 = zacc0;
            if (l0p) {
                #pragma unroll
                for (int r = 0; r < 16; ++r) pacc0[r] = 0.f;
            }
            if (g >= 1) {
                const u16* hc = hb0 + (size_t)(g - 1) * HSZ2 + hROff;   // plain reads
                const u16* pf = Pt0 + p0Off;
                if (l0p) {
                    #pragma unroll
                    for (int ks = 0; ks < 16; ++ks) {
                        f16x8 a = *(const f16x8*)(hc + ks * 16);
                        acc0  = __builtin_amdgcn_mfma_f32_32x32x16_f16(a, qf0[ks], acc0, 0, 0, 0);
                        pacc0 = __builtin_amdgcn_mfma_f32_32x32x16_f16(a, *(const f16x8*)(pf + ks * 16), pacc0, 0, 0, 0);
                    }
                } else {
                    #pragma unroll
                    for (int ks = 0; ks < 16; ++ks)
                        acc0 = __builtin_amdgcn_mfma_f32_32x32x16_f16(*(const f16x8*)(hc + ks * 16), qf0[ks], acc0, 0, 0, 0);
                }
            }
            stash(acc0);
            __syncthreads();
            #pragma unroll
            for (int j = 0; j < 2; ++j) { int m = rm0 + j; zb0[rn][m] = sum8(m) + bv0; }
            __syncthreads();
            if (tid < 256) {   // cell0 (gate order i, j, f, o)
                float zi = zb0[0 * 8 + ch][cb];
                float zj = zb0[1 * 8 + ch][cb];
                float zf = zb0[2 * 8 + ch][cb];
                float zo = zb0[3 * 8 + ch][cb];
                float cn = sigm(zf + 1.0f) * creg0 + sigm(zi) * tanhf(zj);
                creg0 = cn;
                hst0[cb][ch] = __builtin_bit_cast(u16, (_Float16)(sigm(zo) * tanhf(cn)));
            }
        }

        // ===================== layer 0 proj -> m0 ring =====================
        if (l0pT) {   // standalone tail proj of h0(255) at g=256
            #pragma unroll
            for (int r = 0; r < 16; ++r) pacc0[r] = 0.f;
            const u16* hc = hb0 + (size_t)255 * HSZ2 + hROff;
            const u16* pf = Pt0 + p0Off;
            #pragma unroll
            for (int ks = 0; ks < 16; ++ks)
                pacc0 = __builtin_amdgcn_mfma_f32_32x32x16_f16(*(const f16x8*)(hc + ks * 16), *(const f16x8*)(pf + ks * 16), pacc0, 0, 0, 0);
        }
        if (l0p || l0pT) {
            __syncthreads();
            stash(pacc0);
            __syncthreads();
            const int mi = g - 1;
            float* mrow = m0r + (size_t)mi * MSZ;
            #pragma unroll
            for (int j = 0; j < 2; ++j) {
                int m = rm0 + j;
                ast32(mrow + (size_t)m * 640 + l0tb * 32 + rn, sum8(m));
            }
        }

        // ===================== layer 1 gate (s = g-2) =====================
        if (doL1) {
            f32x16 acc1 = xp1(s);
            if (l1p) {
                #pragma unroll
                for (int r = 0; r < 16; ++r) pacc1[r] = 0.f;
            }
            if (s >= 1) {
                const u16* hc = hb1 + (size_t)(s - 1) * HSZ2 + hROff;   // plain reads
                const u16* pf = Pt1 + p1Off;
                if (l1p) {
                    #pragma unroll
                    for (int ks = 0; ks < 16; ++ks) {
                        f16x8 a = *(const f16x8*)(hc + ks * 16);
                        acc1  = __builtin_amdgcn_mfma_f32_32x32x16_f16(a, qf1[ks], acc1, 0, 0, 0);
                        pacc1 = __builtin_amdgcn_mfma_f32_32x32x16_f16(a, *(const f16x8*)(pf + ks * 16), pacc1, 0, 0, 0);
                    }
                } else {
                    #pragma unroll
                    for (int ks = 0; ks < 16; ++ks)
                        acc1 = __builtin_amdgcn_mfma_f32_32x32x16_f16(*(const f16x8*)(hc + ks * 16), qf1[ks], acc1, 0, 0, 0);
                }
            }
            __syncthreads();    // part free
            stash(acc1);
            __syncthreads();
            #pragma unroll
            for (int j = 0; j < 2; ++j) { int m = rm0 + j; zb1[rn][m] = sum8(m) + bv1; }
            __syncthreads();
            if (tid < 256) {   // cell1
                float zi = zb1[0 * 8 + ch][cb];
                float zj = zb1[1 * 8 + ch][cb];
                float zf = zb1[2 * 8 + ch][cb];
                float zo = zb1[3 * 8 + ch][cb];
                float cn = sigm(zf + 1.0f) * creg1 + sigm(zi) * tanhf(zj);
                creg1 = cn;
                hst1[cb][ch] = __builtin_bit_cast(u16, (_Float16)(sigm(zo) * tanhf(cn)));
            }
        }

        // ===================== publish + arrive =====================
        __syncthreads();
        if (doL0 && wid == 0) {
            int b = tid >> 1, hf = tid & 1;
            u64 v = *(const u64*)&hst0[b][hf * 4];
            ast64(hb0 + (size_t)g * HSZ2 + (size_t)b * 2048 + bid * 8 + hf * 4, v);
        }
        if (doL1 && wid == 1) {
            int l = tid - 64;
            int b = l >> 1, hf = l & 1;
            u64 v = *(const u64*)&hst1[b][hf * 4];
            ast64(hb1 + (size_t)s * HSZ2 + (size_t)b * 2048 + bid * 8 + hf * 4, v);
        }
        __syncthreads();   // drains every wave's stores (h0, h1, m0) before flag
        if (tid == 0)
            __hip_atomic_store(arr + bid, (unsigned)(g + 1), __ATOMIC_RELAXED, __HIP_MEMORY_SCOPE_AGENT);

        // ===================== post-arrive (off critical path) =====================
        if (l1p) {   // final output rows for t = s-1 (plain stores; host-read only)
            __syncthreads();
            stash(pacc1);
            __syncthreads();
            #pragma unroll
            for (int j = 0; j < 2; ++j) {
                int m = rm0 + j;
                out[((size_t)m * 256 + (s - 1)) * 640 + l1tb * 32 + rn] = sum8(m);
            }
        }
        if (g < 255) zacc0 = xp0(g + 1);
    }

    // tail: project h1(255) -> out t=255 (parity-1 teams: blocks 60..79)
    if (isL1t && l1par == 1) {
        pollall(arr, 258u);
        f32x16 pacc;
        #pragma unroll
        for (int r = 0; r < 16; ++r) pacc[r] = 0.f;
        const u16* hc = hb1 + (size_t)255 * HSZ2 + hROff;
        const u16* pf = Pt1 + p1Off;
        #pragma unroll
        for (int ks = 0; ks < 16; ++ks)
            pacc = __builtin_amdgcn_mfma_f32_32x32x16_f16(*(const f16x8*)(hc + ks * 16), *(const f16x8*)(pf + ks * 16), pacc, 0, 0, 0);
        stash(pacc);
        __syncthreads();
        #pragma unroll
        for (int j = 0; j < 2; ++j) {
            int m = rm0 + j;
            out[((size_t)m * 256 + 255) * 640 + l1tb * 32 + rn] = sum8(m);
        }
    }
}

// ---------- fallback (R1-style) if ws too small ----------
__device__ __forceinline__ void grid_bar_slow(unsigned int* bar, unsigned int& epoch) {
    __syncthreads();
    epoch++;
    if (threadIdx.x == 0) {
        __threadfence();
        atomicAdd(bar, 1u);
        const unsigned int target = epoch * NBLK;
        while (__hip_atomic_load(bar, __ATOMIC_RELAXED, __HIP_MEMORY_SCOPE_AGENT) < target)
            __builtin_amdgcn_s_sleep(1);
        __threadfence();
    }
    __syncthreads();
}

__global__ void __launch_bounds__(NTHR, 1) lstm_fb(
    const float* __restrict__ x,
    const float* __restrict__ W0, const float* __restrict__ b0, const float* __restrict__ Pr0,
    const float* __restrict__ W1, const float* __restrict__ b1, const float* __restrict__ Pr1,
    float* out, float* ws) {
    const int tid = threadIdx.x;
    const int bid = blockIdx.x;
    unsigned int* bar = (unsigned int*)ws;
    float* mbuf0 = ws + 1024;
    float* mbuf1 = mbuf0 + 32 * 640;
    float* hws = mbuf1 + 32 * 640;
    __shared__ float zbuf[32 * 33];
    __shared__ float pred[512];
    unsigned int epoch = 0;
    const int c_idx = tid & 31;
    const int bg = tid >> 5;
    const int b0r = bg * 2;
    const int col = (c_idx >> 3) * 2048 + bid * 8 + (c_idx & 7);
    const int ch = tid >> 5;
    const int cb = tid & 31;
    const int p_s = (bid * 640) / NBLK;
    const int p_e = ((bid + 1) * 640) / NBLK;
    const int np = p_e - p_s;
    const int kq_n = (np == 2) ? 8 : 4;
    const int klen = 2048 / kq_n;
    const int pg = tid >> 5;
    const bool pact = pg < np * kq_n;
    const int pj = pact ? (pg % np) : 0;
    const int kq = pact ? (pg / np) : 0;
    for (int layer = 0; layer < 2; ++layer) {
        const float* W = layer ? W1 : W0;
        const float* bbv = layer ? b1 : b0;
        const float* Pr = layer ? Pr1 : Pr0;
        const float* inb = layer ? (const float*)out : x;
        for (int i = bid * NTHR + tid; i < 32 * 640; i += NBLK * NTHR) mbuf0[i] = 0.0f;
        float creg = 0.0f;
        grid_bar_slow(bar, epoch);
        const float bias = bbv[col];
        for (int t = 0; t < 256; ++t) {
            float* mcur = (t & 1) ? mbuf1 : mbuf0;
            float* mnxt = (t & 1) ? mbuf0 : mbuf1;
            const float* in0 = inb + (size_t)(b0r * 256 + t) * 640;
            const float* in1 = in0 + (size_t)256 * 640;
            const float* wp = W + col;
            float a0 = 0.f, a1 = 0.f;
            #pragma unroll 4
            for (int k = 0; k < 640; k += 4) {
                float4 u0 = *(const float4*)(in0 + k);
                float4 u1 = *(const float4*)(in1 + k);
                float w0 = wp[(size_t)(k + 0) * 8192], w1 = wp[(size_t)(k + 1) * 8192];
                float w2 = wp[(size_t)(k + 2) * 8192], w3 = wp[(size_t)(k + 3) * 8192];
                a0 += w0 * u0.x + w1 * u0.y + w2 * u0.z + w3 * u0.w;
                a1 += w0 * u1.x + w1 * u1.y + w2 * u1.z + w3 * u1.w;
            }
            const float* q0 = mcur + (size_t)b0r * 640;
            const float* q1 = q0 + 640;
            #pragma unroll 4
            for (int k = 0; k < 640; k += 4) {
                float4 u0 = *(const float4*)(q0 + k);
                float4 u1 = *(const float4*)(q1 + k);
                float w0 = wp[(size_t)(640 + k + 0) * 8192], w1 = wp[(size_t)(640 + k + 1) * 8192];
                float w2 = wp[(size_t)(640 + k + 2) * 8192], w3 = wp[(size_t)(640 + k + 3) * 8192];
                a0 += w0 * u0.x + w1 * u0.y + w2 * u0.z + w3 * u0.w;
                a1 += w0 * u1.x + w1 * u1.y + w2 * u1.z + w3 * u1.w;
            }
            zbuf[c_idx * 33 + b0r + 0] = a0 + bias;
            zbuf[c_idx * 33 + b0r + 1] = a1 + bias;
            __syncthreads();
            if (tid < 256) {
                float zi = zbuf[(0 * 8 + ch) * 33 + cb];
                float zj = zbuf[(1 * 8 + ch) * 33 + cb];
                float zf = zbuf[(2 * 8 + ch) * 33 + cb];
                float zo = zbuf[(3 * 8 + ch) * 33 + cb];
                float cn = sigm(zf + 1.0f) * creg + sigm(zi) * tanhf(zj);
                creg = cn;
                hws[(size_t)(bid * 8 + ch) * 32 + cb] = sigm(zo) * tanhf(cn);
            }
            grid_bar_slow(bar, epoch);
            if (pact) {
                const int p = p_s + pj;
                const float* pp = Pr + p;
                const int k0 = kq * klen;
                float s = 0.f;
                #pragma unroll 4
                for (int k = k0; k < k0 + klen; ++k) s += hws[(size_t)k * 32 + cb] * pp[(size_t)k * 640];
                pred[(pj * 32 + cb) * kq_n + kq] = s;
            }
            __syncthreads();
            if (tid < np * 32) {
                float s = 0.f;
                for (int q2 = 0; q2 < kq_n; ++q2) s += pred[tid * kq_n + q2];
                const int p = p_s + (tid >> 5);
                const int b = tid & 31;
                mnxt[(size_t)b * 640 + p] = s;
                out[((size_t)b * 256 + t) * 640 + p] = s;
            }
            grid_bar_slow(bar, epoch);
        }
    }
}

extern "C" void kernel_launch(void* const* d_in, const int* in_sizes, int n_in,
                              void* d_out, int out_size, void* d_ws, size_t ws_size,
                              hipStream_t stream) {
    const float* x   = (const float*)d_in[0];
    const float* W0  = (const float*)d_in[1];
    const float* b0  = (const float*)d_in[2];
    const float* P0  = (const float*)d_in[3];
    const float* W1  = (const float*)d_in[4];
    const float* b1  = (const float*)d_in[5];
    const float* P1  = (const float*)d_in[6];
    float* out = (float*)d_out;

    // ws layout (bytes, 256-aligned chunks)
    size_t off = 0;
    auto alloc = [&](size_t bytes) { size_t o = off; off += (bytes + 255) & ~(size_t)255; return o; };
    const size_t oBar = alloc(32768);             // arr[256] compact
    const size_t szW  = (size_t)8192 * 1280 * 2;  // Wt bf16 plane
    const size_t szQ  = (size_t)8192 * 2048 * 2;  // Qt f16
    const size_t szPt = (size_t)640 * 2048 * 2;   // Pt f16
    const size_t oWH0 = alloc(szW), oWL0 = alloc(szW), oWH1 = alloc(szW), oWL1 = alloc(szW);
    const size_t oQt0 = alloc(szQ), oQt1 = alloc(szQ);
    const size_t oPt0 = alloc(szPt), oPt1 = alloc(szPt);
    const size_t oH0  = alloc((size_t)256 * HSZ2 * 2);   // no-reuse h rings
    const size_t oH1  = alloc((size_t)256 * HSZ2 * 2);
    const size_t oM0  = alloc((size_t)256 * MSZ * 4);    // no-reuse m0 ring
    const size_t need = off;

    hipMemsetAsync(d_ws, 0, 32768, stream);  // barrier flags start at 0 every call

    if (ws_size < need) {  // fallback path (~0.5 MB ws)
        float* ws = (float*)d_ws;
        void* args[] = {(void*)&x, (void*)&W0, (void*)&b0, (void*)&P0,
                        (void*)&W1, (void*)&b1, (void*)&P1, (void*)&out, (void*)&ws};
        hipError_t err = hipLaunchCooperativeKernel((const void*)lstm_fb,
                                                    dim3(NBLK), dim3(NTHR), args, 0, stream);
        if (err != hipSuccess)
            lstm_fb<<<dim3(NBLK), dim3(NTHR), 0, stream>>>(x, W0, b0, P0, W1, b1, P1, out, ws);
        return;
    }

    char* w = (char*)d_ws;
    u16 *WH0p = (u16*)(w + oWH0), *WL0p = (u16*)(w + oWL0);
    u16 *WH1p = (u16*)(w + oWH1), *WL1p = (u16*)(w + oWL1);
    u16 *Qt0p = (u16*)(w + oQt0), *Qt1p = (u16*)(w + oQt1);
    u16 *Pt0p = (u16*)(w + oPt0), *Pt1p = (u16*)(w + oPt1);
    u16 *hb0p = (u16*)(w + oH0), *hb1p = (u16*)(w + oH1);
    float* m0rp = (float*)(w + oM0);
    unsigned* arrp = (unsigned*)(w + oBar);

    // precompute: weight transposes + Q = P @ Wm (inside the graph, every call)
    transpose_split<<<dim3(256, 40), 256, 0, stream>>>(W0, WH0p, WL0p, 1280, 8192);
    transpose_split<<<dim3(256, 40), 256, 0, stream>>>(W1, WH1p, WL1p, 1280, 8192);
    transpose_f16<<<dim3(20, 64), 256, 0, stream>>>(P0, Pt0p, 2048, 640);
    transpose_f16<<<dim3(20, 64), 256, 0, stream>>>(P1, Pt1p, 2048, 640);
    qgemm<<<dim3(4096), 256, 0, stream>>>(P0, WH0p, WL0p, Qt0p);
    qgemm<<<dim3(4096), 256, 0, stream>>>(P1, WH1p, WL1p, Qt1p);

    const float *b0c = b0, *b1c = b1;
    void* args[] = {(void*)&x, (void*)&b0c, (void*)&b1c,
                    (void*)&WH0p, (void*)&WL0p, (void*)&WH1p, (void*)&WL1p,
                    (void*)&Qt0p, (void*)&Qt1p, (void*)&Pt0p, (void*)&Pt1p,
                    (void*)&hb0p, (void*)&hb1p, (void*)&m0rp,
                    (void*)&out, (void*)&arrp};
    hipError_t err = hipLaunchCooperativeKernel((const void*)lstm_pipe,
                                                dim3(NBLK), dim3(NTHR), args, 0, stream);
    if (err != hipSuccess)
        lstm_pipe<<<dim3(NBLK), dim3(NTHR), 0, stream>>>(
            x, b0c, b1c, WH0p, WL0p, WH1p, WL1p, Qt0p, Qt1p, Pt0p, Pt1p,
            hb0p, hb1p, m0rp, out, arrp);
}

// Round 10
// 6126.894 us; speedup vs baseline: 13.4750x; 1.1779x over previous
//
#include <hip/hip_runtime.h>
#include <math.h>

typedef __attribute__((ext_vector_type(8))) short s16x8;
typedef __attribute__((ext_vector_type(8))) _Float16 f16x8;
typedef __attribute__((ext_vector_type(16))) float f32x16;
typedef unsigned long long u64;
typedef unsigned short u16;

#define NBLK 256
#define NTHR 512

constexpr int HSZ2 = 32 * 2048;  // one h slot, f16 elems
constexpr int MSZH = 32 * 640;   // one m0 slot, f16 elems

__device__ __forceinline__ float sigm(float v) { return 1.0f / (1.0f + expf(-v)); }

__device__ __forceinline__ unsigned short bf16_rne(float x) {
    unsigned u = __float_as_uint(x);
    return (unsigned short)((u + 0x7FFFu + ((u >> 16) & 1u)) >> 16);
}
__device__ __forceinline__ void split2(float x, unsigned short& hi, unsigned short& lo) {
    unsigned u = __float_as_uint(x);
    hi = (unsigned short)(u >> 16);
    float hf = __uint_as_float(u & 0xFFFF0000u);
    lo = bf16_rne(x - hf);
}
__device__ __forceinline__ void split8(const float* f, s16x8& h, s16x8& l) {
    #pragma unroll
    for (int i = 0; i < 8; ++i) {
        unsigned short hh, ll;
        split2(f[i], hh, ll);
        h[i] = (short)hh; l[i] = (short)ll;
    }
}

// ---- agent-scope stores (publish path; readers use plain cached loads on no-reuse slots) ----
__device__ __forceinline__ void ast64(u16* p, u64 v) {
    __hip_atomic_store((u64*)p, v, __ATOMIC_RELAXED, __HIP_MEMORY_SCOPE_AGENT);
}
__device__ __forceinline__ void ast16(u16* p, u16 v) {
    __hip_atomic_store(p, v, __ATOMIC_RELAXED, __HIP_MEMORY_SCOPE_AGENT);
}

// ---- all-poll barrier ----
__device__ __forceinline__ void pollall(const unsigned* arr, unsigned e) {
    if (threadIdx.x < 64) {
        const int i0 = (int)threadIdx.x * 4;
        for (;;) {
            bool ok = (__hip_atomic_load(arr + i0 + 0, __ATOMIC_RELAXED, __HIP_MEMORY_SCOPE_AGENT) >= e) &&
                      (__hip_atomic_load(arr + i0 + 1, __ATOMIC_RELAXED, __HIP_MEMORY_SCOPE_AGENT) >= e) &&
                      (__hip_atomic_load(arr + i0 + 2, __ATOMIC_RELAXED, __HIP_MEMORY_SCOPE_AGENT) >= e) &&
                      (__hip_atomic_load(arr + i0 + 3, __ATOMIC_RELAXED, __HIP_MEMORY_SCOPE_AGENT) >= e);
            if (__all(ok)) break;
            __builtin_amdgcn_s_sleep(1);
        }
    }
    __syncthreads();
}

// ---------- precompute: transpose [R][C] fp32 -> [C][R] bf16 hi/lo ----------
__global__ void transpose_split(const float* __restrict__ in,
                                u16* __restrict__ outHi, u16* __restrict__ outLo,
                                int R, int C) {
    __shared__ float tile[32][33];
    const int c0 = blockIdx.x * 32, r0 = blockIdx.y * 32;
    const int tid = threadIdx.x;  // 256
    {
        int r = tid >> 3, q = (tid & 7) * 4;
        float4 v = *(const float4*)(in + (size_t)(r0 + r) * C + c0 + q);
        tile[q + 0][r] = v.x; tile[q + 1][r] = v.y;
        tile[q + 2][r] = v.z; tile[q + 3][r] = v.w;
    }
    __syncthreads();
    {
        int c = tid >> 3, q = (tid & 7) * 4;
        ushort4 h, l;
        unsigned short hh, ll;
        split2(tile[c][q + 0], hh, ll); h.x = hh; l.x = ll;
        split2(tile[c][q + 1], hh, ll); h.y = hh; l.y = ll;
        split2(tile[c][q + 2], hh, ll); h.z = hh; l.z = ll;
        split2(tile[c][q + 3], hh, ll); h.w = hh; l.w = ll;
        size_t o = (size_t)(c0 + c) * R + r0 + q;
        *(ushort4*)(outHi + o) = h;
        *(ushort4*)(outLo + o) = l;
    }
}

// ---------- precompute: transpose [R][C] fp32 -> [C][R] f16 ----------
__global__ void transpose_f16(const float* __restrict__ in, u16* __restrict__ outp,
                              int R, int C) {
    __shared__ float tile[32][33];
    const int c0 = blockIdx.x * 32, r0 = blockIdx.y * 32;
    const int tid = threadIdx.x;  // 256
    {
        int r = tid >> 3, q = (tid & 7) * 4;
        float4 v = *(const float4*)(in + (size_t)(r0 + r) * C + c0 + q);
        tile[q + 0][r] = v.x; tile[q + 1][r] = v.y;
        tile[q + 2][r] = v.z; tile[q + 3][r] = v.w;
    }
    __syncthreads();
    {
        int c = tid >> 3, q = (tid & 7) * 4;
        ushort4 o;
        o.x = __builtin_bit_cast(u16, (_Float16)tile[c][q + 0]);
        o.y = __builtin_bit_cast(u16, (_Float16)tile[c][q + 1]);
        o.z = __builtin_bit_cast(u16, (_Float16)tile[c][q + 2]);
        o.w = __builtin_bit_cast(u16, (_Float16)tile[c][q + 3]);
        *(ushort4*)(outp + (size_t)(c0 + c) * R + r0 + q) = o;
    }
}

// ---------- precompute: x f32 -> f16 (same layout) ----------
__global__ void xcast(const float* __restrict__ in, u16* __restrict__ outp, int n4) {
    int i = blockIdx.x * blockDim.x + threadIdx.x;
    if (i < n4) {
        float4 v = ((const float4*)in)[i];
        ushort4 o;
        o.x = __builtin_bit_cast(u16, (_Float16)v.x);
        o.y = __builtin_bit_cast(u16, (_Float16)v.y);
        o.z = __builtin_bit_cast(u16, (_Float16)v.z);
        o.w = __builtin_bit_cast(u16, (_Float16)v.w);
        ((ushort4*)outp)[i] = o;
    }
}

// ---------- precompute: Qt[8192][2048] f16 = (P[2048][640] @ Wm[640][8192])^T ----------
__global__ void __launch_bounds__(256) qgemm(const float* __restrict__ P,
    const u16* __restrict__ WH, const u16* __restrict__ WL,
    u16* __restrict__ Qt) {
    const int tid = threadIdx.x;
    const int wid = tid >> 6, lane = tid & 63;
    const int n = lane & 31, kg = lane >> 5;
    const int tile = blockIdx.x * 4 + wid;
    const int ct = tile & 255, kt = tile >> 8;
    const int col = ct * 32 + n;
    const int krow = kt * 32 + n;

    f32x16 acc;
    #pragma unroll
    for (int r = 0; r < 16; ++r) acc[r] = 0.f;

    const float* ap = P + (size_t)krow * 640 + kg * 8;
    const u16* bhp = WH + (size_t)col * 1280 + 640 + kg * 8;
    const u16* blp = WL + (size_t)col * 1280 + 640 + kg * 8;
    #pragma unroll 4
    for (int ks = 0; ks < 40; ++ks) {
        float4 v0 = *(const float4*)(ap + ks * 16);
        float4 v1 = *(const float4*)(ap + ks * 16 + 4);
        float f[8] = {v0.x, v0.y, v0.z, v0.w, v1.x, v1.y, v1.z, v1.w};
        s16x8 ah, al;
        split8(f, ah, al);
        s16x8 bh = *(const s16x8*)(bhp + ks * 16);
        s16x8 bl = *(const s16x8*)(blp + ks * 16);
        acc = __builtin_amdgcn_mfma_f32_32x32x16_bf16(ah, bh, acc, 0, 0, 0);
        acc = __builtin_amdgcn_mfma_f32_32x32x16_bf16(ah, bl, acc, 0, 0, 0);
        acc = __builtin_amdgcn_mfma_f32_32x32x16_bf16(al, bh, acc, 0, 0, 0);
    }
    u16* qrow = Qt + (size_t)col * 2048 + kt * 32 + 4 * kg;
    #pragma unroll
    for (int q = 0; q < 4; ++q) {
        ushort4 o;
        o.x = __builtin_bit_cast(u16, (_Float16)acc[4 * q + 0]);
        o.y = __builtin_bit_cast(u16, (_Float16)acc[4 * q + 1]);
        o.z = __builtin_bit_cast(u16, (_Float16)acc[4 * q + 2]);
        o.w = __builtin_bit_cast(u16, (_Float16)acc[4 * q + 3]);
        *(ushort4*)(qrow + 8 * q) = o;
    }
}

// ---------- main persistent kernel ----------
// Q0/Q1 fragments PINNED in VGPRs via opaque asm (R9 lesson: without pinning the
// compiler rematerializes 128 VGPRs of Q loads every step -> 65 MB/interval L2 thrash).
// All other recurring operands are f16 single-plane so the per-XCD set fits L2.
__global__ void __launch_bounds__(NTHR, 2) lstm_pipe(
    const u16* __restrict__ xh,
    const float* __restrict__ bias0, const float* __restrict__ bias1,
    const u16* __restrict__ Wxt0, const u16* __restrict__ Wxt1,
    const u16* __restrict__ Qt0, const u16* __restrict__ Qt1,
    const u16* __restrict__ Pt0, const u16* __restrict__ Pt1,
    u16* __restrict__ hb0, u16* __restrict__ hb1,   // [256][32][2048] f16 each
    u16* __restrict__ m0r,                          // [256][32][640] f16
    float* out, unsigned* arr) {
    __shared__ float part[8][64][20];
    __shared__ float zb0[32][33];
    __shared__ float zb1[32][33];
    __shared__ u16 hst0[32][8];
    __shared__ u16 hst1[32][8];

    const int tid = threadIdx.x, bid = blockIdx.x;
    const int wid = tid >> 6, lane = tid & 63;
    const int n = lane & 31, kg = lane >> 5;

    const int colmap = (n >> 3) * 2048 + bid * 8 + (n & 7);
    const size_t wx640 = (size_t)colmap * 640 + wid * 80 + kg * 8;    // Wxt0/Wxt1 slice
    const size_t qOff  = (size_t)colmap * 2048 + wid * 256 + kg * 8;  // Qt slice
    const size_t aXh   = (size_t)n * (256 * 640) + wid * 80 + kg * 8; // xh row n, +t*640
    const size_t aM    = (size_t)n * 640 + wid * 80 + kg * 8;         // m0 slot row n
    const size_t hROff = (size_t)n * 2048 + wid * 256 + kg * 8;       // h frag base

    // D layout: col=lane&31, row=(reg&3)+8*(reg>>2)+4*(lane>>5)
    const int rn = tid >> 4, rm0 = (tid & 15) * 2;
    const int ch = tid >> 5, cb = tid & 31;   // cell mapping (tid<256)

    const bool isL0t = bid < 40;
    const int  l0tb  = (bid < 20) ? bid : bid - 20;
    const int  l0par = (bid < 20) ? 0 : 1;
    const bool isL1t = (bid >= 40 && bid < 80);
    const int  l1tb  = (bid < 60) ? bid - 40 : bid - 60;
    const int  l1par = (bid < 60) ? 0 : 1;
    const size_t p0Off = (size_t)(l0tb * 32 + n) * 2048 + wid * 256 + kg * 8;
    const size_t p1Off = (size_t)(l1tb * 32 + n) * 2048 + wid * 256 + kg * 8;

    const float bv0 = bias0[(rn >> 3) * 2048 + bid * 8 + (rn & 7)];
    const float bv1 = bias1[(rn >> 3) * 2048 + bid * 8 + (rn & 7)];

    // ---- load + PIN both layers' Q fragments (128 VGPRs, opaque to remat) ----
    uint4 q0r[16], q1r[16];
    #pragma unroll
    for (int ks = 0; ks < 16; ++ks) {
        q0r[ks] = *(const uint4*)(Qt0 + qOff + ks * 16);
        q1r[ks] = *(const uint4*)(Qt1 + qOff + ks * 16);
    }
    #pragma unroll
    for (int ks = 0; ks < 16; ++ks) {
        asm volatile("" : "+v"(q0r[ks].x), "+v"(q0r[ks].y), "+v"(q0r[ks].z), "+v"(q0r[ks].w));
        asm volatile("" : "+v"(q1r[ks].x), "+v"(q1r[ks].y), "+v"(q1r[ks].z), "+v"(q1r[ks].w));
    }

    float creg0 = 0.f, creg1 = 0.f;

    auto xp0 = [&](int t) -> f32x16 {   // xh(t) @ Wxt0, f16, 5 MFMAs
        f32x16 a;
        #pragma unroll
        for (int r = 0; r < 16; ++r) a[r] = 0.f;
        const u16* xb = xh + aXh + (size_t)t * 640;
        const u16* wb = Wxt0 + wx640;
        #pragma unroll
        for (int ks = 0; ks < 5; ++ks)
            a = __builtin_amdgcn_mfma_f32_32x32x16_f16(*(const f16x8*)(xb + ks * 16),
                                                       *(const f16x8*)(wb + ks * 16), a, 0, 0, 0);
        return a;
    };
    auto xp1 = [&](int s) -> f32x16 {   // m0(s) @ Wxt1, f16, 5 MFMAs (no-reuse slot, plain loads)
        f32x16 a;
        #pragma unroll
        for (int r = 0; r < 16; ++r) a[r] = 0.f;
        const u16* mb = m0r + (size_t)s * MSZH + aM;
        const u16* wb = Wxt1 + wx640;
        #pragma unroll
        for (int ks = 0; ks < 5; ++ks)
            a = __builtin_amdgcn_mfma_f32_32x32x16_f16(*(const f16x8*)(mb + ks * 16),
                                                       *(const f16x8*)(wb + ks * 16), a, 0, 0, 0);
        return a;
    };
    auto stash = [&](const f32x16& v) {
        #pragma unroll
        for (int r = 0; r < 4; ++r) {
            float4 w;
            w.x = v[4 * r + 0]; w.y = v[4 * r + 1];
            w.z = v[4 * r + 2]; w.w = v[4 * r + 3];
            *(float4*)&part[wid][lane][4 * r] = w;
        }
    };
    auto sum8 = [&](int m) -> float {
        int lp = rn + 32 * ((m >> 2) & 1);
        int rg = (m & 3) + 4 * (m >> 3);
        float s = 0.f;
        #pragma unroll
        for (int w = 0; w < 8; ++w) s += part[w][lp][rg];
        return s;
    };

    f32x16 zacc0 = xp0(0);

    for (int g = 0; g <= 257; ++g) {
        if (g > 0) pollall(arr, (unsigned)g);
        const int s = g - 2;
        const bool doL0 = (g <= 255);
        const bool doL1 = (s >= 0);
        const bool l0p  = isL0t && g >= 1 && g <= 255 && (((g - 1) & 1) == l0par);
        const bool l0pT = isL0t && g == 256 && (((g - 1) & 1) == l0par);
        const bool l1p  = isL1t && s >= 1 && (((s - 1) & 1) == l1par);

        f32x16 pacc0, pacc1;

        // ===================== layer 0 gate =====================
        if (doL0) {
            f32x16 acc0 = zacc0;
            if (l0p) {
                #pragma unroll
                for (int r = 0; r < 16; ++r) pacc0[r] = 0.f;
            }
            if (g >= 1) {
                const u16* hc = hb0 + (size_t)(g - 1) * HSZ2 + hROff;
                const u16* pf = Pt0 + p0Off;
                if (l0p) {
                    #pragma unroll
                    for (int ks = 0; ks < 16; ++ks) {
                        f16x8 a = *(const f16x8*)(hc + ks * 16);
                        acc0  = __builtin_amdgcn_mfma_f32_32x32x16_f16(a, __builtin_bit_cast(f16x8, q0r[ks]), acc0, 0, 0, 0);
                        pacc0 = __builtin_amdgcn_mfma_f32_32x32x16_f16(a, *(const f16x8*)(pf + ks * 16), pacc0, 0, 0, 0);
                    }
                } else {
                    #pragma unroll
                    for (int ks = 0; ks < 16; ++ks)
                        acc0 = __builtin_amdgcn_mfma_f32_32x32x16_f16(*(const f16x8*)(hc + ks * 16),
                                                                      __builtin_bit_cast(f16x8, q0r[ks]), acc0, 0, 0, 0);
                }
            }
            stash(acc0);
            __syncthreads();
            #pragma unroll
            for (int j = 0; j < 2; ++j) { int m = rm0 + j; zb0[rn][m] = sum8(m) + bv0; }
            __syncthreads();
            if (tid < 256) {   // cell0 (gate order i, j, f, o)
                float zi = zb0[0 * 8 + ch][cb];
                float zj = zb0[1 * 8 + ch][cb];
                float zf = zb0[2 * 8 + ch][cb];
                float zo = zb0[3 * 8 + ch][cb];
                float cn = sigm(zf + 1.0f) * creg0 + sigm(zi) * tanhf(zj);
                creg0 = cn;
                hst0[cb][ch] = __builtin_bit_cast(u16, (_Float16)(sigm(zo) * tanhf(cn)));
            }
        }

        // ===================== layer 0 proj -> m0 ring (f16) =====================
        if (l0pT) {
            #pragma unroll
            for (int r = 0; r < 16; ++r) pacc0[r] = 0.f;
            const u16* hc = hb0 + (size_t)255 * HSZ2 + hROff;
            const u16* pf = Pt0 + p0Off;
            #pragma unroll
            for (int ks = 0; ks < 16; ++ks)
                pacc0 = __builtin_amdgcn_mfma_f32_32x32x16_f16(*(const f16x8*)(hc + ks * 16),
                                                               *(const f16x8*)(pf + ks * 16), pacc0, 0, 0, 0);
        }
        if (l0p || l0pT) {
            __syncthreads();
            stash(pacc0);
            __syncthreads();
            u16* mrow = m0r + (size_t)(g - 1) * MSZH;
            #pragma unroll
            for (int j = 0; j < 2; ++j) {
                int m = rm0 + j;
                ast16(mrow + (size_t)m * 640 + l0tb * 32 + rn,
                      __builtin_bit_cast(u16, (_Float16)sum8(m)));
            }
        }

        // ===================== layer 1 gate (s = g-2) =====================
        if (doL1) {
            f32x16 acc1 = xp1(s);
            if (l1p) {
                #pragma unroll
                for (int r = 0; r < 16; ++r) pacc1[r] = 0.f;
            }
            if (s >= 1) {
                const u16* hc = hb1 + (size_t)(s - 1) * HSZ2 + hROff;
                const u16* pf = Pt1 + p1Off;
                if (l1p) {
                    #pragma unroll
                    for (int ks = 0; ks < 16; ++ks) {
                        f16x8 a = *(const f16x8*)(hc + ks * 16);
                        acc1  = __builtin_amdgcn_mfma_f32_32x32x16_f16(a, __builtin_bit_cast(f16x8, q1r[ks]), acc1, 0, 0, 0);
                        pacc1 = __builtin_amdgcn_mfma_f32_32x32x16_f16(a, *(const f16x8*)(pf + ks * 16), pacc1, 0, 0, 0);
                    }
                } else {
                    #pragma unroll
                    for (int ks = 0; ks < 16; ++ks)
                        acc1 = __builtin_amdgcn_mfma_f32_32x32x16_f16(*(const f16x8*)(hc + ks * 16),
                                                                      __builtin_bit_cast(f16x8, q1r[ks]), acc1, 0, 0, 0);
                }
            }
            __syncthreads();    // part free
            stash(acc1);
            __syncthreads();
            #pragma unroll
            for (int j = 0; j < 2; ++j) { int m = rm0 + j; zb1[rn][m] = sum8(m) + bv1; }
            __syncthreads();
            if (tid < 256) {   // cell1
                float zi = zb1[0 * 8 + ch][cb];
                float zj = zb1[1 * 8 + ch][cb];
                float zf = zb1[2 * 8 + ch][cb];
                float zo = zb1[3 * 8 + ch][cb];
                float cn = sigm(zf + 1.0f) * creg1 + sigm(zi) * tanhf(zj);
                creg1 = cn;
                hst1[cb][ch] = __builtin_bit_cast(u16, (_Float16)(sigm(zo) * tanhf(cn)));
            }
        }

        // ===================== publish + arrive =====================
        __syncthreads();
        if (doL0 && wid == 0) {
            int b = tid >> 1, hf = tid & 1;
            u64 v = *(const u64*)&hst0[b][hf * 4];
            ast64(hb0 + (size_t)g * HSZ2 + (size_t)b * 2048 + bid * 8 + hf * 4, v);
        }
        if (doL1 && wid == 1) {
            int l = tid - 64;
            int b = l >> 1, hf = l & 1;
            u64 v = *(const u64*)&hst1[b][hf * 4];
            ast64(hb1 + (size_t)s * HSZ2 + (size_t)b * 2048 + bid * 8 + hf * 4, v);
        }
        __syncthreads();   // drains every wave's stores before flag
        if (tid == 0)
            __hip_atomic_store(arr + bid, (unsigned)(g + 1), __ATOMIC_RELAXED, __HIP_MEMORY_SCOPE_AGENT);

        // ===================== post-arrive (off critical path) =====================
        if (l1p) {
            __syncthreads();
            stash(pacc1);
            __syncthreads();
            #pragma unroll
            for (int j = 0; j < 2; ++j) {
                int m = rm0 + j;
                out[((size_t)m * 256 + (s - 1)) * 640 + l1tb * 32 + rn] = sum8(m);
            }
        }
        if (g < 255) zacc0 = xp0(g + 1);
    }

    // tail: project h1(255) -> out t=255 (parity-1 teams)
    if (isL1t && l1par == 1) {
        pollall(arr, 258u);
        f32x16 pacc;
        #pragma unroll
        for (int r = 0; r < 16; ++r) pacc[r] = 0.f;
        const u16* hc = hb1 + (size_t)255 * HSZ2 + hROff;
        const u16* pf = Pt1 + p1Off;
        #pragma unroll
        for (int ks = 0; ks < 16; ++ks)
            pacc = __builtin_amdgcn_mfma_f32_32x32x16_f16(*(const f16x8*)(hc + ks * 16),
                                                          *(const f16x8*)(pf + ks * 16), pacc, 0, 0, 0);
        stash(pacc);
        __syncthreads();
        #pragma unroll
        for (int j = 0; j < 2; ++j) {
            int m = rm0 + j;
            out[((size_t)m * 256 + 255) * 640 + l1tb * 32 + rn] = sum8(m);
        }
    }
}

// ---------- fallback (R1-style) if ws too small ----------
__device__ __forceinline__ void grid_bar_slow(unsigned int* bar, unsigned int& epoch) {
    __syncthreads();
    epoch++;
    if (threadIdx.x == 0) {
        __threadfence();
        atomicAdd(bar, 1u);
        const unsigned int target = epoch * NBLK;
        while (__hip_atomic_load(bar, __ATOMIC_RELAXED, __HIP_MEMORY_SCOPE_AGENT) < target)
            __builtin_amdgcn_s_sleep(1);
        __threadfence();
    }
    __syncthreads();
}

__global__ void __launch_bounds__(NTHR, 1) lstm_fb(
    const float* __restrict__ x,
    const float* __restrict__ W0, const float* __restrict__ b0, const float* __restrict__ Pr0,
    const float* __restrict__ W1, const float* __restrict__ b1, const float* __restrict__ Pr1,
    float* out, float* ws) {
    const int tid = threadIdx.x;
    const int bid = blockIdx.x;
    unsigned int* bar = (unsigned int*)ws;
    float* mbuf0 = ws + 1024;
    float* mbuf1 = mbuf0 + 32 * 640;
    float* hws = mbuf1 + 32 * 640;
    __shared__ float zbuf[32 * 33];
    __shared__ float pred[512];
    unsigned int epoch = 0;
    const int c_idx = tid & 31;
    const int bg = tid >> 5;
    const int b0r = bg * 2;
    const int col = (c_idx >> 3) * 2048 + bid * 8 + (c_idx & 7);
    const int ch = tid >> 5;
    const int cb = tid & 31;
    const int p_s = (bid * 640) / NBLK;
    const int p_e = ((bid + 1) * 640) / NBLK;
    const int np = p_e - p_s;
    const int kq_n = (np == 2) ? 8 : 4;
    const int klen = 2048 / kq_n;
    const int pg = tid >> 5;
    const bool pact = pg < np * kq_n;
    const int pj = pact ? (pg % np) : 0;
    const int kq = pact ? (pg / np) : 0;
    for (int layer = 0; layer < 2; ++layer) {
        const float* W = layer ? W1 : W0;
        const float* bbv = layer ? b1 : b0;
        const float* Pr = layer ? Pr1 : Pr0;
        const float* inb = layer ? (const float*)out : x;
        for (int i = bid * NTHR + tid; i < 32 * 640; i += NBLK * NTHR) mbuf0[i] = 0.0f;
        float creg = 0.0f;
        grid_bar_slow(bar, epoch);
        const float bias = bbv[col];
        for (int t = 0; t < 256; ++t) {
            float* mcur = (t & 1) ? mbuf1 : mbuf0;
            float* mnxt = (t & 1) ? mbuf0 : mbuf1;
            const float* in0 = inb + (size_t)(b0r * 256 + t) * 640;
            const float* in1 = in0 + (size_t)256 * 640;
            const float* wp = W + col;
            float a0 = 0.f, a1 = 0.f;
            #pragma unroll 4
            for (int k = 0; k < 640; k += 4) {
                float4 u0 = *(const float4*)(in0 + k);
                float4 u1 = *(const float4*)(in1 + k);
                float w0 = wp[(size_t)(k + 0) * 8192], w1 = wp[(size_t)(k + 1) * 8192];
                float w2 = wp[(size_t)(k + 2) * 8192], w3 = wp[(size_t)(k + 3) * 8192];
                a0 += w0 * u0.x + w1 * u0.y + w2 * u0.z + w3 * u0.w;
                a1 += w0 * u1.x + w1 * u1.y + w2 * u1.z + w3 * u1.w;
            }
            const float* q0 = mcur + (size_t)b0r * 640;
            const float* q1 = q0 + 640;
            #pragma unroll 4
            for (int k = 0; k < 640; k += 4) {
                float4 u0 = *(const float4*)(q0 + k);
                float4 u1 = *(const float4*)(q1 + k);
                float w0 = wp[(size_t)(640 + k + 0) * 8192], w1 = wp[(size_t)(640 + k + 1) * 8192];
                float w2 = wp[(size_t)(640 + k + 2) * 8192], w3 = wp[(size_t)(640 + k + 3) * 8192];
                a0 += w0 * u0.x + w1 * u0.y + w2 * u0.z + w3 * u0.w;
                a1 += w0 * u1.x + w1 * u1.y + w2 * u1.z + w3 * u1.w;
            }
            zbuf[c_idx * 33 + b0r + 0] = a0 + bias;
            zbuf[c_idx * 33 + b0r + 1] = a1 + bias;
            __syncthreads();
            if (tid < 256) {
                float zi = zbuf[(0 * 8 + ch) * 33 + cb];
                float zj = zbuf[(1 * 8 + ch) * 33 + cb];
                float zf = zbuf[(2 * 8 + ch) * 33 + cb];
                float zo = zbuf[(3 * 8 + ch) * 33 + cb];
                float cn = sigm(zf + 1.0f) * creg + sigm(zi) * tanhf(zj);
                creg = cn;
                hws[(size_t)(bid * 8 + ch) * 32 + cb] = sigm(zo) * tanhf(cn);
            }
            grid_bar_slow(bar, epoch);
            if (pact) {
                const int p = p_s + pj;
                const float* pp = Pr + p;
                const int k0 = kq * klen;
                float s = 0.f;
                #pragma unroll 4
                for (int k = k0; k < k0 + klen; ++k) s += hws[(size_t)k * 32 + cb] * pp[(size_t)k * 640];
                pred[(pj * 32 + cb) * kq_n + kq] = s;
            }
            __syncthreads();
            if (tid < np * 32) {
                float s = 0.f;
                for (int q2 = 0; q2 < kq_n; ++q2) s += pred[tid * kq_n + q2];
                const int p = p_s + (tid >> 5);
                const int b = tid & 31;
                mnxt[(size_t)b * 640 + p] = s;
                out[((size_t)b * 256 + t) * 640 + p] = s;
            }
            grid_bar_slow(bar, epoch);
        }
    }
}

extern "C" void kernel_launch(void* const* d_in, const int* in_sizes, int n_in,
                              void* d_out, int out_size, void* d_ws, size_t ws_size,
                              hipStream_t stream) {
    const float* x   = (const float*)d_in[0];
    const float* W0  = (const float*)d_in[1];
    const float* b0  = (const float*)d_in[2];
    const float* P0  = (const float*)d_in[3];
    const float* W1  = (const float*)d_in[4];
    const float* b1  = (const float*)d_in[5];
    const float* P1  = (const float*)d_in[6];
    float* out = (float*)d_out;

    // ws layout (bytes, 256-aligned). One shared transpose-plane pair reused by both qgemms.
    size_t off = 0;
    auto alloc = [&](size_t bytes) { size_t o = off; off += (bytes + 255) & ~(size_t)255; return o; };
    const size_t oBar = alloc(32768);
    const size_t szW  = (size_t)8192 * 1280 * 2;  // bf16 plane (scratch, reused)
    const size_t szQ  = (size_t)8192 * 2048 * 2;  // Qt f16
    const size_t szPt = (size_t)640 * 2048 * 2;   // Pt f16
    const size_t szWx = (size_t)8192 * 640 * 2;   // Wxt f16
    const size_t oWH  = alloc(szW), oWL = alloc(szW);
    const size_t oQt0 = alloc(szQ), oQt1 = alloc(szQ);
    const size_t oPt0 = alloc(szPt), oPt1 = alloc(szPt);
    const size_t oWx0 = alloc(szWx), oWx1 = alloc(szWx);
    const size_t oXh  = alloc((size_t)32 * 256 * 640 * 2);
    const size_t oH0  = alloc((size_t)256 * HSZ2 * 2);   // no-reuse h rings
    const size_t oH1  = alloc((size_t)256 * HSZ2 * 2);
    const size_t oM0  = alloc((size_t)256 * MSZH * 2);   // no-reuse m0 ring (f16)
    const size_t need = off;

    hipMemsetAsync(d_ws, 0, 32768, stream);  // barrier flags start at 0 every call

    if (ws_size < need) {  // fallback path (~0.5 MB ws)
        float* ws = (float*)d_ws;
        void* args[] = {(void*)&x, (void*)&W0, (void*)&b0, (void*)&P0,
                        (void*)&W1, (void*)&b1, (void*)&P1, (void*)&out, (void*)&ws};
        hipError_t err = hipLaunchCooperativeKernel((const void*)lstm_fb,
                                                    dim3(NBLK), dim3(NTHR), args, 0, stream);
        if (err != hipSuccess)
            lstm_fb<<<dim3(NBLK), dim3(NTHR), 0, stream>>>(x, W0, b0, P0, W1, b1, P1, out, ws);
        return;
    }

    char* w = (char*)d_ws;
    u16 *WHp = (u16*)(w + oWH), *WLp = (u16*)(w + oWL);
    u16 *Qt0p = (u16*)(w + oQt0), *Qt1p = (u16*)(w + oQt1);
    u16 *Pt0p = (u16*)(w + oPt0), *Pt1p = (u16*)(w + oPt1);
    u16 *Wx0p = (u16*)(w + oWx0), *Wx1p = (u16*)(w + oWx1);
    u16 *xhp  = (u16*)(w + oXh);
    u16 *hb0p = (u16*)(w + oH0), *hb1p = (u16*)(w + oH1);
    u16 *m0rp = (u16*)(w + oM0);
    unsigned* arrp = (unsigned*)(w + oBar);

    // precompute (stream-ordered; plane pair reused between the two qgemms)
    transpose_split<<<dim3(256, 40), 256, 0, stream>>>(W0, WHp, WLp, 1280, 8192);
    qgemm<<<dim3(4096), 256, 0, stream>>>(P0, WHp, WLp, Qt0p);
    transpose_split<<<dim3(256, 40), 256, 0, stream>>>(W1, WHp, WLp, 1280, 8192);
    qgemm<<<dim3(4096), 256, 0, stream>>>(P1, WHp, WLp, Qt1p);
    transpose_f16<<<dim3(20, 64), 256, 0, stream>>>(P0, Pt0p, 2048, 640);
    transpose_f16<<<dim3(20, 64), 256, 0, stream>>>(P1, Pt1p, 2048, 640);
    transpose_f16<<<dim3(256, 20), 256, 0, stream>>>(W0, Wx0p, 640, 8192);
    transpose_f16<<<dim3(256, 20), 256, 0, stream>>>(W1, Wx1p, 640, 8192);
    xcast<<<dim3(5120), 256, 0, stream>>>(x, xhp, 32 * 256 * 640 / 4);

    const float *b0c = b0, *b1c = b1;
    void* args[] = {(void*)&xhp, (void*)&b0c, (void*)&b1c,
                    (void*)&Wx0p, (void*)&Wx1p,
                    (void*)&Qt0p, (void*)&Qt1p, (void*)&Pt0p, (void*)&Pt1p,
                    (void*)&hb0p, (void*)&hb1p, (void*)&m0rp,
                    (void*)&out, (void*)&arrp};
    hipError_t err = hipLaunchCooperativeKernel((const void*)lstm_pipe,
                                                dim3(NBLK), dim3(NTHR), args, 0, stream);
    if (err != hipSuccess)
        lstm_pipe<<<dim3(NBLK), dim3(NTHR), 0, stream>>>(
            xhp, b0c, b1c, Wx0p, Wx1p, Qt0p, Qt1p, Pt0p, Pt1p,
            hb0p, hb1p, m0rp, out, arrp);
}